// Round 9
// baseline (542.543 us; speedup 1.0000x reference)
//
#include <hip/hip_runtime.h>

// Problem constants: S=1024, B=8, E=1024, H=16, HD=64
#define M_TOK 8192   // S*B
#define SEQ   1024
#define NB    8
#define EMB   1024
#define NH    16

typedef float  f32x4 __attribute__((ext_vector_type(4)));
typedef __bf16 bf16x8 __attribute__((ext_vector_type(8)));
typedef unsigned short u16x8 __attribute__((ext_vector_type(8)));
typedef unsigned short u16x4 __attribute__((ext_vector_type(4)));

__device__ __forceinline__ unsigned short f2bf(float f) {
  unsigned int u = __builtin_bit_cast(unsigned int, f);
  return (unsigned short)((u + 0x7fffu + ((u >> 16) & 1u)) >> 16);
}

__device__ __forceinline__ f32x4 mfma_bf16(u16x8 a, u16x8 b, f32x4 c) {
  return __builtin_amdgcn_mfma_f32_16x16x32_bf16(
      __builtin_bit_cast(bf16x8, a), __builtin_bit_cast(bf16x8, b), c, 0, 0, 0);
}

__device__ __forceinline__ void gload_lds16(const void* g, void* l) {
  __builtin_amdgcn_global_load_lds(
      (const __attribute__((address_space(1))) void*)g,
      (__attribute__((address_space(3))) void*)l, 16, 0, 0);
}

// ---------------------------------------------------------------- converts
__global__ __launch_bounds__(256) void cvt_kernel(const float* __restrict__ src,
                                                  unsigned short* __restrict__ dst,
                                                  int n) {
  int i = (blockIdx.x * 256 + threadIdx.x) * 4;
  if (i >= n) return;
  float4 v = *reinterpret_cast<const float4*>(src + i);
  u16x4 o = {f2bf(v.x), f2bf(v.y), f2bf(v.z), f2bf(v.w)};
  *reinterpret_cast<u16x4*>(dst + i) = o;
}

// batched activation convert: 6 tensors of 8388608 f32, grid (8192, 6)
__global__ __launch_bounds__(256) void cvt6_kernel(
    const float* __restrict__ s0, const float* __restrict__ s1,
    const float* __restrict__ s2, const float* __restrict__ s3,
    const float* __restrict__ s4, const float* __restrict__ s5,
    unsigned short* __restrict__ d0, unsigned short* __restrict__ d1,
    unsigned short* __restrict__ d2, unsigned short* __restrict__ d3,
    unsigned short* __restrict__ d4, unsigned short* __restrict__ d5) {
  int which = blockIdx.y;
  const float* src = (which == 0) ? s0 : (which == 1) ? s1 : (which == 2) ? s2
                     : (which == 3) ? s3 : (which == 4) ? s4 : s5;
  unsigned short* dst = (which == 0) ? d0 : (which == 1) ? d1 : (which == 2) ? d2
                        : (which == 3) ? d3 : (which == 4) ? d4 : d5;
  int i = (blockIdx.x * 256 + threadIdx.x) * 4;
  float4 v = *reinterpret_cast<const float4*>(src + i);
  u16x4 o = {f2bf(v.x), f2bf(v.y), f2bf(v.z), f2bf(v.w)};
  *reinterpret_cast<u16x4*>(dst + i) = o;
}

// ---------------------------------------------------------------- QKV proj
// 128x128 tile. A-fragments stream DIRECTLY from global (L2) into registers —
// no A LDS staging (halves LDS traffic). W staged via gload_lds, XOR-swizzled
// combined [128][re32|im32] tile. Per-batch m-tiles; XCD swizzle 1536 = 8x192.
__global__ __launch_bounds__(256, 2) void proj_gemm(
    const unsigned short* __restrict__ qreb, const unsigned short* __restrict__ qimb,
    const unsigned short* __restrict__ kreb, const unsigned short* __restrict__ kimb,
    const unsigned short* __restrict__ vreb, const unsigned short* __restrict__ vimb,
    const unsigned short* __restrict__ wr, const unsigned short* __restrict__ wi,
    const float* __restrict__ br, const float* __restrict__ bi,
    unsigned short* __restrict__ q2, unsigned short* __restrict__ k2,
    unsigned short* __restrict__ vt) {
  __shared__ __align__(16) unsigned short smem[18432];  // 36864 B
  unsigned short (*sW)[64] = (unsigned short (*)[64])(smem);          // [128][64]
  unsigned short (*sC)[140]  = (unsigned short (*)[140])(smem);       // epilogue m-major
  unsigned short (*sCt)[144] = (unsigned short (*)[144])(smem);       // epilogue n-major

  const int tid = threadIdx.x;
  const int lane = tid & 63;
  const int w = tid >> 6;
  const int lr = lane & 15, lk = lane >> 4;
  const int wm = (w & 1) * 64, wn = (w >> 1) * 64;

  // XCD-aware bijective work swizzle: 1536 blocks = 8 XCD x 192
  const int lin = blockIdx.x + blockIdx.y * 24;
  const int wg = (lin & 7) * 192 + (lin >> 3);
  const int n0 = (wg % 24) * 128;
  const int mt = wg / 24;
  const int sec = n0 >> 10;
  const int bb = mt & 7;
  const int ss0 = (mt >> 3) * 128;
  const int h_base = (n0 & 1023) >> 6;

  const unsigned short* aRe = (sec == 0) ? qreb : ((sec == 1) ? kreb : vreb);
  const unsigned short* aIm = (sec == 0) ? qimb : ((sec == 1) ? kimb : vimb);

  // W staging indices (granule gid = c*256+tid; row = gid>>3; g = gid&7)
  int srow[4], sgsw[4];
  for (int c = 0; c < 4; ++c) {
    int gid = c * 256 + tid;
    srow[c] = gid >> 3;
    sgsw[c] = (gid & 7) ^ (srow[c] & 7);
  }

  // A-fragment global pointers (frag = 16 contiguous bytes of the A row)
  const unsigned short* pAr[4];
  const unsigned short* pAi[4];
#pragma unroll
  for (int mi = 0; mi < 4; ++mi) {
    int grow = (ss0 + wm + mi * 16 + lr) * 8 + bb;
    pAr[mi] = aRe + (size_t)grow * 1024 + lk * 8;
    pAi[mi] = aIm + (size_t)grow * 1024 + lk * 8;
  }

  f32x4 accre[4][4], accim[4][4];
  for (int i = 0; i < 4; ++i)
    for (int j = 0; j < 4; ++j) {
      accre[i][j] = {0.f, 0.f, 0.f, 0.f};
      accim[i][j] = {0.f, 0.f, 0.f, 0.f};
    }
  const u16x8 sign8 = {0x8000, 0x8000, 0x8000, 0x8000, 0x8000, 0x8000, 0x8000, 0x8000};

#pragma unroll 1
  for (int k0 = 0; k0 < 1024; k0 += 32) {
    // A fragments: direct global loads (drained by the barrier's vmcnt(0))
    u16x8 ar_[4], ai_[4];
#pragma unroll
    for (int mi = 0; mi < 4; ++mi) {
      ar_[mi] = *(const u16x8*)(pAr[mi] + k0);
      ai_[mi] = *(const u16x8*)(pAi[mi] + k0);
    }
    // W staging (async to LDS)
#pragma unroll
    for (int c = 0; c < 4; ++c) {
      int row = srow[c], gsw = sgsw[c];
      int kcol = k0 + (gsw & 3) * 8;
      size_t woff = (size_t)(n0 + row) * 1024 + kcol;
      gload_lds16((gsw < 4 ? wr : wi) + woff, smem + (c * 256 + w * 64) * 8);
    }
    __syncthreads();

    u16x8 fWr[4], fWi[4];
#pragma unroll
    for (int ni = 0; ni < 4; ++ni) {
      int R = wn + ni * 16 + lr, sw = R & 7;
      fWr[ni] = *(const u16x8*)&sW[R][(lk ^ sw) * 8];
      fWi[ni] = *(const u16x8*)&sW[R][((4 + lk) ^ sw) * 8];
    }
#pragma unroll
    for (int mi = 0; mi < 4; ++mi) {
      u16x8 nai = ai_[mi] ^ sign8;
#pragma unroll
      for (int ni = 0; ni < 4; ++ni) {
        accre[mi][ni] = mfma_bf16(ar_[mi], fWr[ni], accre[mi][ni]);
        accre[mi][ni] = mfma_bf16(nai, fWi[ni], accre[mi][ni]);
        accim[mi][ni] = mfma_bf16(ar_[mi], fWi[ni], accim[mi][ni]);
        accim[mi][ni] = mfma_bf16(ai_[mi], fWr[ni], accim[mi][ni]);
      }
    }
    __syncthreads();
  }

  float vbr[4], vbi[4];
  for (int ni = 0; ni < 4; ++ni) {
    int nabs = n0 + wn + ni * 16 + lr;
    vbr[ni] = br[nabs];
    vbi[ni] = bi[nabs];
  }

  if (sec < 2) {
    unsigned short* dst = (sec == 0) ? q2 : k2;
#define QK_PASS(ACC, BV, POFF)                                                  \
    for (int ni = 0; ni < 4; ++ni)                                              \
      for (int mi = 0; mi < 4; ++mi)                                            \
        for (int r = 0; r < 4; ++r)                                             \
          sC[wm + mi * 16 + lk * 4 + r][wn + ni * 16 + lr] =                    \
              f2bf(ACC[mi][ni][r] + BV[ni]);                                    \
    __syncthreads();                                                            \
    for (int it = 0; it < 8; ++it) {                                            \
      int c = it * 256 + tid;                                                   \
      int m = c >> 4, sub = c & 15, h_i = sub >> 3, d8 = sub & 7;               \
      u16x8 v = *(const u16x8*)&sC[m][h_i * 64 + d8 * 8];                       \
      size_t addr = ((size_t)((bb * 16 + h_base + h_i) * 1024 + ss0 + m)) * 128 \
                    + POFF + d8 * 8;                                            \
      *(u16x8*)(dst + addr) = v;                                                \
    }                                                                           \
    __syncthreads();
    QK_PASS(accre, vbr, 0)
    QK_PASS(accim, vbi, 64)
#undef QK_PASS
  } else {
#define VT_PASS(ACC, BV, POFF)                                                  \
    for (int ni = 0; ni < 4; ++ni)                                              \
      for (int mi = 0; mi < 4; ++mi)                                            \
        for (int r = 0; r < 4; ++r)                                             \
          sCt[wn + ni * 16 + lr][wm + mi * 16 + lk * 4 + r] =                   \
              f2bf(ACC[mi][ni][r] + BV[ni]);                                    \
    __syncthreads();                                                            \
    for (int it = 0; it < 8; ++it) {                                            \
      int c = it * 256 + tid;                                                   \
      int nl = c >> 4, sub = c & 15;                                            \
      int h_i = nl >> 6, d = nl & 63;                                           \
      u16x8 v = *(const u16x8*)&sCt[nl][sub * 8];                               \
      size_t addr = ((size_t)(bb * 16 + h_base + h_i) * 128 + d + POFF) * 1024  \
                    + ss0 + sub * 8;                                            \
      *(u16x8*)(vt + addr) = v;                                                 \
    }                                                                           \
    __syncthreads();
    VT_PASS(accre, vbr, 0)
    VT_PASS(accim, vbi, 64)
#undef VT_PASS
  }
}

// ---------------------------------------------------------------- attention
// 1D grid 2048, XCD-locality mapping. 4 waves x 16 q-rows. Q in registers.
// Single-buffer K/V (replay-proven sync: stage -> sync -> compute -> sync).
// LDS tiles XOR-swizzled (16B granule ^= row&7) via pre-swizzled global source.
__global__ __launch_bounds__(256, 2) void attn_kernel(
    const unsigned short* __restrict__ q2, const unsigned short* __restrict__ k2,
    const unsigned short* __restrict__ vt,
    unsigned short* __restrict__ aor, unsigned short* __restrict__ aoi) {
  __shared__ unsigned short sK[64][128];   // 16 KB
  __shared__ unsigned short sV[128][64];   // 16 KB
  __shared__ unsigned short sP[4][16][72]; // ~9 KB, +8 pad

  const int tid = threadIdx.x, lane = tid & 63, w = tid >> 6;
  const int lr = lane & 15, lk = lane >> 4;
  const int lin = blockIdx.x;
  const int idx = lin >> 3;
  const int bh = (lin & 7) * 16 + (idx >> 4);
  const int q0 = (idx & 15) * 64;
  const int bb = bh >> 4, hh = bh & 15;

  const unsigned short* kbase = k2 + (size_t)bh * 131072;
  const unsigned short* vbase = vt + (size_t)bh * 131072;

  // Q fragments in registers (16 VGPRs), read once
  const int qrow = q0 + w * 16 + lr;
  u16x8 qf[4];
#pragma unroll
  for (int ks = 0; ks < 4; ++ks)
    qf[ks] = *(const u16x8*)(q2 + (size_t)bh * 131072 + (size_t)qrow * 128 +
                             ks * 32 + lk * 8);

  f32x4 o[8];
#pragma unroll
  for (int i = 0; i < 8; ++i) o[i] = {0.f, 0.f, 0.f, 0.f};
  float mrun[4] = {-1e30f, -1e30f, -1e30f, -1e30f};
  float lrun[4] = {0.f, 0.f, 0.f, 0.f};
  const float SC = 0.125f;  // 1/sqrt(64)

#pragma unroll 1
  for (int t0 = 0; t0 < 1024; t0 += 64) {
    // stage K tile (64 x 128), swizzled source
    const unsigned short* kb = kbase + (size_t)t0 * 128;
#pragma unroll
    for (int c = 0; c < 4; ++c) {
      int rb = (w * 4 + c) * 4;
      int row = rb + (lane >> 4);
      int blk = (lane & 15) ^ (row & 7);
      gload_lds16(kb + (size_t)row * 128 + blk * 8, &sK[rb][0]);
    }
    // stage V tile (128 x 64), swizzled source
    const unsigned short* vb = vbase + t0;
#pragma unroll
    for (int c = 0; c < 4; ++c) {
      int rb = (w * 4 + c) * 8;
      int row = rb + (lane >> 3);
      int blk = (lane & 7) ^ (row & 7);
      gload_lds16(vb + (size_t)row * 1024 + blk * 8, &sV[rb][0]);
    }
    __syncthreads();

    // scores tile: rows = wave's 16 q-rows, cols = 64 t
    f32x4 sc[4];
#pragma unroll
    for (int nj = 0; nj < 4; ++nj) sc[nj] = {0.f, 0.f, 0.f, 0.f};
    __builtin_amdgcn_s_setprio(1);
#pragma unroll
    for (int ks = 0; ks < 4; ++ks) {
#pragma unroll
      for (int nj = 0; nj < 4; ++nj) {
        int krow = nj * 16 + lr;
        u16x8 kf = *(const u16x8*)&sK[krow][((ks * 4 + lk) ^ (krow & 7)) * 8];
        sc[nj] = mfma_bf16(qf[ks], kf, sc[nj]);
      }
    }
    __builtin_amdgcn_s_setprio(0);

    // online softmax (row r of this lane = 4*lk + r)
#pragma unroll
    for (int r = 0; r < 4; ++r) {
      float s0 = sc[0][r] * SC, s1 = sc[1][r] * SC;
      float s2 = sc[2][r] * SC, s3 = sc[3][r] * SC;
      float mx = fmaxf(fmaxf(s0, s1), fmaxf(s2, s3));
      for (int msk = 1; msk < 16; msk <<= 1) mx = fmaxf(mx, __shfl_xor(mx, msk));
      float mnew = fmaxf(mrun[r], mx);
      float corr = __expf(mrun[r] - mnew);
      float p0 = __expf(s0 - mnew), p1 = __expf(s1 - mnew);
      float p2 = __expf(s2 - mnew), p3 = __expf(s3 - mnew);
      float rs = p0 + p1 + p2 + p3;
      for (int msk = 1; msk < 16; msk <<= 1) rs += __shfl_xor(rs, msk);
      lrun[r] = lrun[r] * corr + rs;
      mrun[r] = mnew;
#pragma unroll
      for (int ni = 0; ni < 8; ++ni) o[ni][r] *= corr;
      int prow = lk * 4 + r;
      sP[w][prow][0 * 16 + lr] = f2bf(p0);
      sP[w][prow][1 * 16 + lr] = f2bf(p1);
      sP[w][prow][2 * 16 + lr] = f2bf(p2);
      sP[w][prow][3 * 16 + lr] = f2bf(p3);
    }

    // PV: O[s, dd] += P[s, t] * VT[dd, t]
    __builtin_amdgcn_s_setprio(1);
#pragma unroll
    for (int ks = 0; ks < 2; ++ks) {
      u16x8 pf = *(const u16x8*)&sP[w][lr][ks * 32 + lk * 8];
#pragma unroll
      for (int ni = 0; ni < 8; ++ni) {
        int vrow = ni * 16 + lr;
        u16x8 vf = *(const u16x8*)&sV[vrow][((ks * 4 + lk) ^ (vrow & 7)) * 8];
        o[ni] = mfma_bf16(pf, vf, o[ni]);
      }
    }
    __builtin_amdgcn_s_setprio(0);
    __syncthreads();
  }

#pragma unroll
  for (int r = 0; r < 4; ++r) {
    float inv = 1.0f / lrun[r];
#pragma unroll
    for (int ni = 0; ni < 8; ++ni) o[ni][r] *= inv;
  }
#pragma unroll
  for (int ni = 0; ni < 8; ++ni) {
    int dd = ni * 16 + lr;
#pragma unroll
    for (int r = 0; r < 4; ++r) {
      int sg = q0 + w * 16 + lk * 4 + r;
      size_t tok = (size_t)sg * 8 + bb;
      if (dd < 64)
        aor[tok * 1024 + hh * 64 + dd] = f2bf(o[ni][r]);
      else
        aoi[tok * 1024 + hh * 64 + (dd - 64)] = f2bf(o[ni][r]);
    }
  }
}

// ---------------------------------------------------------------- out proj
// A-fragments direct from global; W staged (combined [128][re32|im32],
// XOR-swizzled). XCD swizzle (512 = 8 x 64).
__global__ __launch_bounds__(256, 2) void out_gemm(
    const unsigned short* __restrict__ ar, const unsigned short* __restrict__ ai,
    const unsigned short* __restrict__ wr, const unsigned short* __restrict__ wi,
    const float* __restrict__ br, const float* __restrict__ bi,
    float* __restrict__ out) {
  __shared__ __align__(16) unsigned short smem[8192];  // 16 KB (W only)
  unsigned short (*sW)[64] = (unsigned short (*)[64])(smem);

  const int tid = threadIdx.x;
  const int lane = tid & 63;
  const int w = tid >> 6;
  const int lr = lane & 15, lk = lane >> 4;
  const int wm = (w & 1) * 64, wn = (w >> 1) * 64;

  const int lin = blockIdx.x;
  const int wg = (lin & 7) * 64 + (lin >> 3);
  const int n0 = (wg & 7) * 128;
  const int m0 = (wg >> 3) * 128;

  int srow[4], sgsw[4];
  for (int c = 0; c < 4; ++c) {
    int gid = c * 256 + tid;
    srow[c] = gid >> 3;
    sgsw[c] = (gid & 7) ^ (srow[c] & 7);
  }

  const unsigned short* pAr[4];
  const unsigned short* pAi[4];
#pragma unroll
  for (int mi = 0; mi < 4; ++mi) {
    int grow = m0 + wm + mi * 16 + lr;
    pAr[mi] = ar + (size_t)grow * 1024 + lk * 8;
    pAi[mi] = ai + (size_t)grow * 1024 + lk * 8;
  }

  f32x4 accre[4][4], accim[4][4];
  for (int i = 0; i < 4; ++i)
    for (int j = 0; j < 4; ++j) {
      accre[i][j] = {0.f, 0.f, 0.f, 0.f};
      accim[i][j] = {0.f, 0.f, 0.f, 0.f};
    }
  const u16x8 sign8 = {0x8000, 0x8000, 0x8000, 0x8000, 0x8000, 0x8000, 0x8000, 0x8000};

#pragma unroll 1
  for (int k0 = 0; k0 < 1024; k0 += 32) {
    u16x8 ar_[4], ai_[4];
#pragma unroll
    for (int mi = 0; mi < 4; ++mi) {
      ar_[mi] = *(const u16x8*)(pAr[mi] + k0);
      ai_[mi] = *(const u16x8*)(pAi[mi] + k0);
    }
#pragma unroll
    for (int c = 0; c < 4; ++c) {
      int row = srow[c], gsw = sgsw[c];
      int kcol = k0 + (gsw & 3) * 8;
      size_t woff = (size_t)(n0 + row) * 1024 + kcol;
      gload_lds16((gsw < 4 ? wr : wi) + woff, smem + (c * 256 + w * 64) * 8);
    }
    __syncthreads();

    u16x8 fWr[4], fWi[4];
#pragma unroll
    for (int ni = 0; ni < 4; ++ni) {
      int R = wn + ni * 16 + lr, sw = R & 7;
      fWr[ni] = *(const u16x8*)&sW[R][(lk ^ sw) * 8];
      fWi[ni] = *(const u16x8*)&sW[R][((4 + lk) ^ sw) * 8];
    }
#pragma unroll
    for (int mi = 0; mi < 4; ++mi) {
      u16x8 na_i = ai_[mi] ^ sign8;
#pragma unroll
      for (int ni = 0; ni < 4; ++ni) {
        accre[mi][ni] = mfma_bf16(ar_[mi], fWr[ni], accre[mi][ni]);
        accre[mi][ni] = mfma_bf16(na_i, fWi[ni], accre[mi][ni]);
        accim[mi][ni] = mfma_bf16(ar_[mi], fWi[ni], accim[mi][ni]);
        accim[mi][ni] = mfma_bf16(ai_[mi], fWr[ni], accim[mi][ni]);
      }
    }
    __syncthreads();
  }

  for (int ni = 0; ni < 4; ++ni) {
    int n = n0 + wn + ni * 16 + lr;
    float vbr = br[n], vbi = bi[n];
    for (int mi = 0; mi < 4; ++mi) {
      for (int r = 0; r < 4; ++r) {
        int m = m0 + wm + mi * 16 + lk * 4 + r;
        out[(size_t)m * 1024 + n] = accre[mi][ni][r] + vbr;
        out[8388608 + (size_t)m * 1024 + n] = accim[mi][ni][r] + vbi;
      }
    }
  }
}

// ---------------------------------------------------------------- launch
extern "C" void kernel_launch(void* const* d_in, const int* in_sizes, int n_in,
                              void* d_out, int out_size, void* d_ws, size_t ws_size,
                              hipStream_t stream) {
  const float* qre = (const float*)d_in[0];
  const float* qim = (const float*)d_in[1];
  const float* kre = (const float*)d_in[2];
  const float* kim = (const float*)d_in[3];
  const float* vre = (const float*)d_in[4];
  const float* vim = (const float*)d_in[5];
  const float* wqkv_re = (const float*)d_in[6];
  const float* wqkv_im = (const float*)d_in[7];
  const float* bqr = (const float*)d_in[8];
  const float* bqi = (const float*)d_in[9];
  const float* wo_re = (const float*)d_in[10];
  const float* wo_im = (const float*)d_in[11];
  const float* bor = (const float*)d_in[12];
  const float* boi = (const float*)d_in[13];

  char* ws = (char*)d_ws;
  unsigned short* wr_bf  = (unsigned short*)(ws + 0);          //  6.29 MB
  unsigned short* wi_bf  = (unsigned short*)(ws + 6291456);
  unsigned short* wor_bf = (unsigned short*)(ws + 12582912);
  unsigned short* woi_bf = (unsigned short*)(ws + 14680064);
  // activation bf16 (dead after proj_gemm)
  unsigned short* qreb   = (unsigned short*)(ws + 16777216);
  unsigned short* qimb   = (unsigned short*)(ws + 33554432);
  unsigned short* kreb   = (unsigned short*)(ws + 50331648);
  unsigned short* kimb   = (unsigned short*)(ws + 67108864);
  unsigned short* vreb   = (unsigned short*)(ws + 83886080);
  unsigned short* vimb   = (unsigned short*)(ws + 100663296);
  unsigned short* q2     = (unsigned short*)(ws + 117440512);  // 33.55 MB
  unsigned short* k2     = (unsigned short*)(ws + 150994944);
  unsigned short* vt     = (unsigned short*)(ws + 184549376);  // end 218.1 MB
  // attn outputs alias the dead activation region
  unsigned short* aor    = (unsigned short*)(ws + 16777216);
  unsigned short* aoi    = (unsigned short*)(ws + 33554432);

  cvt_kernel<<<3072, 256, 0, stream>>>(wqkv_re, wr_bf, 3145728);
  cvt_kernel<<<3072, 256, 0, stream>>>(wqkv_im, wi_bf, 3145728);
  cvt_kernel<<<1024, 256, 0, stream>>>(wo_re, wor_bf, 1048576);
  cvt_kernel<<<1024, 256, 0, stream>>>(wo_im, woi_bf, 1048576);
  cvt6_kernel<<<dim3(8192, 6), 256, 0, stream>>>(qre, qim, kre, kim, vre, vim,
                                                 qreb, qimb, kreb, kimb, vreb, vimb);

  proj_gemm<<<dim3(24, 64), 256, 0, stream>>>(qreb, qimb, kreb, kimb, vreb, vimb,
                                              wr_bf, wi_bf, bqr, bqi, q2, k2, vt);
  attn_kernel<<<2048, 256, 0, stream>>>(q2, k2, vt, aor, aoi);
  out_gemm<<<512, 256, 0, stream>>>(aor, aoi, wor_bf, woi_bf, bor, boi,
                                    (float*)d_out);
}

// Round 10
// 477.924 us; speedup vs baseline: 1.1352x; 1.1352x over previous
//
#include <hip/hip_runtime.h>

// Problem constants: S=1024, B=8, E=1024, H=16, HD=64
#define M_TOK 8192   // S*B
#define SEQ   1024
#define NB    8
#define EMB   1024
#define NH    16

typedef float  f32x4 __attribute__((ext_vector_type(4)));
typedef __bf16 bf16x8 __attribute__((ext_vector_type(8)));
typedef unsigned short u16x8 __attribute__((ext_vector_type(8)));
typedef unsigned short u16x4 __attribute__((ext_vector_type(4)));

__device__ __forceinline__ unsigned short f2bf(float f) {
  unsigned int u = __builtin_bit_cast(unsigned int, f);
  return (unsigned short)((u + 0x7fffu + ((u >> 16) & 1u)) >> 16);
}

__device__ __forceinline__ f32x4 mfma_bf16(u16x8 a, u16x8 b, f32x4 c) {
  return __builtin_amdgcn_mfma_f32_16x16x32_bf16(
      __builtin_bit_cast(bf16x8, a), __builtin_bit_cast(bf16x8, b), c, 0, 0, 0);
}

__device__ __forceinline__ void gload_lds16(const void* g, void* l) {
  __builtin_amdgcn_global_load_lds(
      (const __attribute__((address_space(1))) void*)g,
      (__attribute__((address_space(3))) void*)l, 16, 0, 0);
}

// ---------------------------------------------------------------- converts
__global__ __launch_bounds__(256) void cvt_kernel(const float* __restrict__ src,
                                                  unsigned short* __restrict__ dst,
                                                  int n) {
  int i = (blockIdx.x * 256 + threadIdx.x) * 4;
  if (i >= n) return;
  float4 v = *reinterpret_cast<const float4*>(src + i);
  u16x4 o = {f2bf(v.x), f2bf(v.y), f2bf(v.z), f2bf(v.w)};
  *reinterpret_cast<u16x4*>(dst + i) = o;
}

// batched activation convert: 6 tensors of 8388608 f32, grid (8192, 6)
__global__ __launch_bounds__(256) void cvt6_kernel(
    const float* __restrict__ s0, const float* __restrict__ s1,
    const float* __restrict__ s2, const float* __restrict__ s3,
    const float* __restrict__ s4, const float* __restrict__ s5,
    unsigned short* __restrict__ d0, unsigned short* __restrict__ d1,
    unsigned short* __restrict__ d2, unsigned short* __restrict__ d3,
    unsigned short* __restrict__ d4, unsigned short* __restrict__ d5) {
  int which = blockIdx.y;
  const float* src = (which == 0) ? s0 : (which == 1) ? s1 : (which == 2) ? s2
                     : (which == 3) ? s3 : (which == 4) ? s4 : s5;
  unsigned short* dst = (which == 0) ? d0 : (which == 1) ? d1 : (which == 2) ? d2
                        : (which == 3) ? d3 : (which == 4) ? d4 : d5;
  int i = (blockIdx.x * 256 + threadIdx.x) * 4;
  float4 v = *reinterpret_cast<const float4*>(src + i);
  u16x4 o = {f2bf(v.x), f2bf(v.y), f2bf(v.z), f2bf(v.w)};
  *reinterpret_cast<u16x4*>(dst + i) = o;
}

// ---------------------------------------------------------------- QKV proj
// (round-8 proven: 128x128 tile, combined [128][re32|im32] XOR-swizzled
// tiles, per-batch m-tiles, XCD swizzle 1536 = 8 x 192)
__global__ __launch_bounds__(256, 2) void proj_gemm(
    const unsigned short* __restrict__ qreb, const unsigned short* __restrict__ qimb,
    const unsigned short* __restrict__ kreb, const unsigned short* __restrict__ kimb,
    const unsigned short* __restrict__ vreb, const unsigned short* __restrict__ vimb,
    const unsigned short* __restrict__ wr, const unsigned short* __restrict__ wi,
    const float* __restrict__ br, const float* __restrict__ bi,
    unsigned short* __restrict__ q2, unsigned short* __restrict__ k2,
    unsigned short* __restrict__ vt) {
  __shared__ __align__(16) unsigned short smem[18432];  // 36864 B
  unsigned short (*sA)[64] = (unsigned short (*)[64])(smem);          // [128][64]
  unsigned short (*sW)[64] = (unsigned short (*)[64])(smem + 8192);   // [128][64]
  unsigned short (*sC)[140]  = (unsigned short (*)[140])(smem);       // epilogue m-major
  unsigned short (*sCt)[144] = (unsigned short (*)[144])(smem);       // epilogue n-major

  const int tid = threadIdx.x;
  const int lane = tid & 63;
  const int w = tid >> 6;
  const int lr = lane & 15, lk = lane >> 4;
  const int wm = (w & 1) * 64, wn = (w >> 1) * 64;

  // XCD-aware bijective work swizzle: 1536 blocks = 8 XCD x 192
  const int lin = blockIdx.x + blockIdx.y * 24;
  const int wg = (lin & 7) * 192 + (lin >> 3);
  const int n0 = (wg % 24) * 128;
  const int mt = wg / 24;
  const int sec = n0 >> 10;
  const int bb = mt & 7;
  const int ss0 = (mt >> 3) * 128;
  const int h_base = (n0 & 1023) >> 6;

  const unsigned short* aRe = (sec == 0) ? qreb : ((sec == 1) ? kreb : vreb);
  const unsigned short* aIm = (sec == 0) ? qimb : ((sec == 1) ? kimb : vimb);

  int srow[4], sgsw[4];
  for (int c = 0; c < 4; ++c) {
    int gid = c * 256 + tid;
    srow[c] = gid >> 3;
    sgsw[c] = (gid & 7) ^ (srow[c] & 7);
  }

  f32x4 accre[4][4], accim[4][4];
  for (int i = 0; i < 4; ++i)
    for (int j = 0; j < 4; ++j) {
      accre[i][j] = {0.f, 0.f, 0.f, 0.f};
      accim[i][j] = {0.f, 0.f, 0.f, 0.f};
    }
  const u16x8 sign8 = {0x8000, 0x8000, 0x8000, 0x8000, 0x8000, 0x8000, 0x8000, 0x8000};

  for (int k0 = 0; k0 < 1024; k0 += 32) {
    for (int c = 0; c < 4; ++c) {
      int row = srow[c], gsw = sgsw[c];
      int kcol = k0 + (gsw & 3) * 8;
      size_t aoff = (size_t)((ss0 + row) * 8 + bb) * 1024 + kcol;
      gload_lds16((gsw < 4 ? aRe : aIm) + aoff, smem + (c * 256 + w * 64) * 8);
      size_t woff = (size_t)(n0 + row) * 1024 + kcol;
      gload_lds16((gsw < 4 ? wr : wi) + woff, smem + 8192 + (c * 256 + w * 64) * 8);
    }
    __syncthreads();

    u16x8 fWr[4], fWi[4];
    for (int ni = 0; ni < 4; ++ni) {
      int R = wn + ni * 16 + lr, sw = R & 7;
      fWr[ni] = *(const u16x8*)&sW[R][(lk ^ sw) * 8];
      fWi[ni] = *(const u16x8*)&sW[R][((4 + lk) ^ sw) * 8];
    }
    for (int mi = 0; mi < 4; ++mi) {
      int R = wm + mi * 16 + lr, sw = R & 7;
      u16x8 ar = *(const u16x8*)&sA[R][(lk ^ sw) * 8];
      u16x8 ai = *(const u16x8*)&sA[R][((4 + lk) ^ sw) * 8];
      u16x8 nai = ai ^ sign8;
      for (int ni = 0; ni < 4; ++ni) {
        accre[mi][ni] = mfma_bf16(ar, fWr[ni], accre[mi][ni]);
        accre[mi][ni] = mfma_bf16(nai, fWi[ni], accre[mi][ni]);
        accim[mi][ni] = mfma_bf16(ar, fWi[ni], accim[mi][ni]);
        accim[mi][ni] = mfma_bf16(ai, fWr[ni], accim[mi][ni]);
      }
    }
    __syncthreads();
  }

  float vbr[4], vbi[4];
  for (int ni = 0; ni < 4; ++ni) {
    int nabs = n0 + wn + ni * 16 + lr;
    vbr[ni] = br[nabs];
    vbi[ni] = bi[nabs];
  }

  if (sec < 2) {
    unsigned short* dst = (sec == 0) ? q2 : k2;
#define QK_PASS(ACC, BV, POFF)                                                  \
    for (int ni = 0; ni < 4; ++ni)                                              \
      for (int mi = 0; mi < 4; ++mi)                                            \
        for (int r = 0; r < 4; ++r)                                             \
          sC[wm + mi * 16 + lk * 4 + r][wn + ni * 16 + lr] =                    \
              f2bf(ACC[mi][ni][r] + BV[ni]);                                    \
    __syncthreads();                                                            \
    for (int it = 0; it < 8; ++it) {                                            \
      int c = it * 256 + tid;                                                   \
      int m = c >> 4, sub = c & 15, h_i = sub >> 3, d8 = sub & 7;               \
      u16x8 v = *(const u16x8*)&sC[m][h_i * 64 + d8 * 8];                       \
      size_t addr = ((size_t)((bb * 16 + h_base + h_i) * 1024 + ss0 + m)) * 128 \
                    + POFF + d8 * 8;                                            \
      *(u16x8*)(dst + addr) = v;                                                \
    }                                                                           \
    __syncthreads();
    QK_PASS(accre, vbr, 0)
    QK_PASS(accim, vbi, 64)
#undef QK_PASS
  } else {
#define VT_PASS(ACC, BV, POFF)                                                  \
    for (int ni = 0; ni < 4; ++ni)                                              \
      for (int mi = 0; mi < 4; ++mi)                                            \
        for (int r = 0; r < 4; ++r)                                             \
          sCt[wn + ni * 16 + lr][wm + mi * 16 + lk * 4 + r] =                   \
              f2bf(ACC[mi][ni][r] + BV[ni]);                                    \
    __syncthreads();                                                            \
    for (int it = 0; it < 8; ++it) {                                            \
      int c = it * 256 + tid;                                                   \
      int nl = c >> 4, sub = c & 15;                                            \
      int h_i = nl >> 6, d = nl & 63;                                           \
      u16x8 v = *(const u16x8*)&sCt[nl][sub * 8];                               \
      size_t addr = ((size_t)(bb * 16 + h_base + h_i) * 128 + d + POFF) * 1024  \
                    + ss0 + sub * 8;                                            \
      *(u16x8*)(vt + addr) = v;                                                 \
    }                                                                           \
    __syncthreads();
    VT_PASS(accre, vbr, 0)
    VT_PASS(accim, vbi, 64)
#undef VT_PASS
  }
}

// ---------------------------------------------------------------- attention
// 1D grid 1024, XCD-locality mapping. QBLK=128: 4 waves x 32 q-rows.
// Q in registers; single-buffer K/V (replay-proven sync); XOR-swizzled tiles;
// defer-max online softmax (THR=8, wave-uniform branch).
__global__ __launch_bounds__(256, 2) void attn_kernel(
    const unsigned short* __restrict__ q2, const unsigned short* __restrict__ k2,
    const unsigned short* __restrict__ vt,
    unsigned short* __restrict__ aor, unsigned short* __restrict__ aoi) {
  __shared__ unsigned short sK[64][128];    // 16 KB
  __shared__ unsigned short sV[128][64];    // 16 KB
  __shared__ unsigned short sP[4][32][72];  // 18 KB, +8 pad

  const int tid = threadIdx.x, lane = tid & 63, w = tid >> 6;
  const int lr = lane & 15, lk = lane >> 4;
  const int lin = blockIdx.x;
  const int idx = lin >> 3;                    // 0..127
  const int bh = (lin & 7) * 16 + (idx >> 3);  // XCD-local bh
  const int q0 = (idx & 7) * 128;
  const int bb = bh >> 4, hh = bh & 15;

  const unsigned short* kbase = k2 + (size_t)bh * 131072;
  const unsigned short* vbase = vt + (size_t)bh * 131072;

  // Q fragments in registers (32 VGPRs), read once
  u16x8 qf[2][4];
#pragma unroll
  for (int fi = 0; fi < 2; ++fi) {
    int row = q0 + w * 32 + fi * 16 + lr;
#pragma unroll
    for (int ks = 0; ks < 4; ++ks)
      qf[fi][ks] = *(const u16x8*)(q2 + (size_t)bh * 131072 + (size_t)row * 128 +
                                   ks * 32 + lk * 8);
  }

  f32x4 o[2][8];
#pragma unroll
  for (int fi = 0; fi < 2; ++fi)
#pragma unroll
    for (int i = 0; i < 8; ++i) o[fi][i] = {0.f, 0.f, 0.f, 0.f};
  float mrun[2][4], lrun[2][4];
#pragma unroll
  for (int fi = 0; fi < 2; ++fi)
#pragma unroll
    for (int r = 0; r < 4; ++r) {
      mrun[fi][r] = -1e30f;
      lrun[fi][r] = 0.f;
    }
  const float SC = 0.125f;  // 1/sqrt(64)

#pragma unroll 1
  for (int t0 = 0; t0 < 1024; t0 += 64) {
    // stage K tile (64 x 128), swizzled source
    const unsigned short* kb = kbase + (size_t)t0 * 128;
#pragma unroll
    for (int c = 0; c < 4; ++c) {
      int rb = (w * 4 + c) * 4;
      int row = rb + (lane >> 4);
      int blk = (lane & 15) ^ (row & 7);
      gload_lds16(kb + (size_t)row * 128 + blk * 8, &sK[rb][0]);
    }
    // stage V tile (128 x 64), swizzled source
    const unsigned short* vb = vbase + t0;
#pragma unroll
    for (int c = 0; c < 4; ++c) {
      int rb = (w * 4 + c) * 8;
      int row = rb + (lane >> 3);
      int blk = (lane & 7) ^ (row & 7);
      gload_lds16(vb + (size_t)row * 1024 + blk * 8, &sV[rb][0]);
    }
    __syncthreads();

#pragma unroll
    for (int fi = 0; fi < 2; ++fi) {
      // scores: this frag's 16 q-rows x 64 t
      f32x4 sc[4];
#pragma unroll
      for (int nj = 0; nj < 4; ++nj) sc[nj] = {0.f, 0.f, 0.f, 0.f};
      __builtin_amdgcn_s_setprio(1);
#pragma unroll
      for (int ks = 0; ks < 4; ++ks) {
#pragma unroll
        for (int nj = 0; nj < 4; ++nj) {
          int krow = nj * 16 + lr;
          u16x8 kf = *(const u16x8*)&sK[krow][((ks * 4 + lk) ^ (krow & 7)) * 8];
          sc[nj] = mfma_bf16(qf[fi][ks], kf, sc[nj]);
        }
      }
      __builtin_amdgcn_s_setprio(0);

#pragma unroll
      for (int nj = 0; nj < 4; ++nj) sc[nj] *= SC;

      // tile max per row + defer decision
      float pmx[4];
      bool need = false;
#pragma unroll
      for (int r = 0; r < 4; ++r) {
        float mx = fmaxf(fmaxf(sc[0][r], sc[1][r]), fmaxf(sc[2][r], sc[3][r]));
        for (int msk = 1; msk < 16; msk <<= 1) mx = fmaxf(mx, __shfl_xor(mx, msk));
        pmx[r] = mx;
        need = need || (mx > mrun[fi][r] + 8.0f);
      }

      if (__any(need)) {
        // full online-softmax update
#pragma unroll
        for (int r = 0; r < 4; ++r) {
          float mnew = fmaxf(mrun[fi][r], pmx[r]);
          float corr = __expf(mrun[fi][r] - mnew);
          float p0 = __expf(sc[0][r] - mnew), p1 = __expf(sc[1][r] - mnew);
          float p2 = __expf(sc[2][r] - mnew), p3 = __expf(sc[3][r] - mnew);
          float rs = p0 + p1 + p2 + p3;
          for (int msk = 1; msk < 16; msk <<= 1) rs += __shfl_xor(rs, msk);
          lrun[fi][r] = lrun[fi][r] * corr + rs;
          mrun[fi][r] = mnew;
#pragma unroll
          for (int ni = 0; ni < 8; ++ni) o[fi][ni][r] *= corr;
          int prow = fi * 16 + lk * 4 + r;
          sP[w][prow][0 * 16 + lr] = f2bf(p0);
          sP[w][prow][1 * 16 + lr] = f2bf(p1);
          sP[w][prow][2 * 16 + lr] = f2bf(p2);
          sP[w][prow][3 * 16 + lr] = f2bf(p3);
        }
      } else {
        // deferred: keep old max, no rescale (P bounded by e^8)
#pragma unroll
        for (int r = 0; r < 4; ++r) {
          float m = mrun[fi][r];
          float p0 = __expf(sc[0][r] - m), p1 = __expf(sc[1][r] - m);
          float p2 = __expf(sc[2][r] - m), p3 = __expf(sc[3][r] - m);
          float rs = p0 + p1 + p2 + p3;
          for (int msk = 1; msk < 16; msk <<= 1) rs += __shfl_xor(rs, msk);
          lrun[fi][r] += rs;
          int prow = fi * 16 + lk * 4 + r;
          sP[w][prow][0 * 16 + lr] = f2bf(p0);
          sP[w][prow][1 * 16 + lr] = f2bf(p1);
          sP[w][prow][2 * 16 + lr] = f2bf(p2);
          sP[w][prow][3 * 16 + lr] = f2bf(p3);
        }
      }
    }

    // PV: O[s, dd] += P[s, t] * VT[dd, t]  (V fragments shared across fi)
    __builtin_amdgcn_s_setprio(1);
#pragma unroll
    for (int ks = 0; ks < 2; ++ks) {
      u16x8 pf0 = *(const u16x8*)&sP[w][lr][ks * 32 + lk * 8];
      u16x8 pf1 = *(const u16x8*)&sP[w][16 + lr][ks * 32 + lk * 8];
#pragma unroll
      for (int ni = 0; ni < 8; ++ni) {
        int vrow = ni * 16 + lr;
        u16x8 vf = *(const u16x8*)&sV[vrow][((ks * 4 + lk) ^ (vrow & 7)) * 8];
        o[0][ni] = mfma_bf16(pf0, vf, o[0][ni]);
        o[1][ni] = mfma_bf16(pf1, vf, o[1][ni]);
      }
    }
    __builtin_amdgcn_s_setprio(0);
    __syncthreads();
  }

#pragma unroll
  for (int fi = 0; fi < 2; ++fi)
#pragma unroll
    for (int r = 0; r < 4; ++r) {
      float inv = 1.0f / lrun[fi][r];
#pragma unroll
      for (int ni = 0; ni < 8; ++ni) o[fi][ni][r] *= inv;
    }
#pragma unroll
  for (int fi = 0; fi < 2; ++fi)
#pragma unroll
    for (int ni = 0; ni < 8; ++ni) {
      int dd = ni * 16 + lr;
#pragma unroll
      for (int r = 0; r < 4; ++r) {
        int sg = q0 + w * 32 + fi * 16 + lk * 4 + r;
        size_t tok = (size_t)sg * 8 + bb;
        if (dd < 64)
          aor[tok * 1024 + hh * 64 + dd] = f2bf(o[fi][ni][r]);
        else
          aoi[tok * 1024 + hh * 64 + (dd - 64)] = f2bf(o[fi][ni][r]);
      }
    }
}

// ---------------------------------------------------------------- out proj
// (round-8 proven: combined [128][re32|im32] XOR-swizzled tiles; XCD swizzle)
__global__ __launch_bounds__(256, 2) void out_gemm(
    const unsigned short* __restrict__ ar, const unsigned short* __restrict__ ai,
    const unsigned short* __restrict__ wr, const unsigned short* __restrict__ wi,
    const float* __restrict__ br, const float* __restrict__ bi,
    float* __restrict__ out) {
  __shared__ __align__(16) unsigned short smem[16384];  // 32 KB
  unsigned short (*sA)[64] = (unsigned short (*)[64])(smem);
  unsigned short (*sW)[64] = (unsigned short (*)[64])(smem + 8192);

  const int tid = threadIdx.x;
  const int lane = tid & 63;
  const int w = tid >> 6;
  const int lr = lane & 15, lk = lane >> 4;
  const int wm = (w & 1) * 64, wn = (w >> 1) * 64;

  const int lin = blockIdx.x;
  const int wg = (lin & 7) * 64 + (lin >> 3);
  const int n0 = (wg & 7) * 128;
  const int m0 = (wg >> 3) * 128;

  int srow[4], sgsw[4];
  for (int c = 0; c < 4; ++c) {
    int gid = c * 256 + tid;
    srow[c] = gid >> 3;
    sgsw[c] = (gid & 7) ^ (srow[c] & 7);
  }

  f32x4 accre[4][4], accim[4][4];
  for (int i = 0; i < 4; ++i)
    for (int j = 0; j < 4; ++j) {
      accre[i][j] = {0.f, 0.f, 0.f, 0.f};
      accim[i][j] = {0.f, 0.f, 0.f, 0.f};
    }
  const u16x8 sign8 = {0x8000, 0x8000, 0x8000, 0x8000, 0x8000, 0x8000, 0x8000, 0x8000};

  for (int k0 = 0; k0 < 1024; k0 += 32) {
    for (int c = 0; c < 4; ++c) {
      int row = srow[c], gsw = sgsw[c];
      int kcol = k0 + (gsw & 3) * 8;
      size_t aoff = (size_t)(m0 + row) * 1024 + kcol;
      gload_lds16((gsw < 4 ? ar : ai) + aoff, smem + (c * 256 + w * 64) * 8);
      size_t woff = (size_t)(n0 + row) * 1024 + kcol;
      gload_lds16((gsw < 4 ? wr : wi) + woff, smem + 8192 + (c * 256 + w * 64) * 8);
    }
    __syncthreads();

    u16x8 fWr[4], fWi[4];
    for (int ni = 0; ni < 4; ++ni) {
      int R = wn + ni * 16 + lr, sw = R & 7;
      fWr[ni] = *(const u16x8*)&sW[R][(lk ^ sw) * 8];
      fWi[ni] = *(const u16x8*)&sW[R][((4 + lk) ^ sw) * 8];
    }
    for (int mi = 0; mi < 4; ++mi) {
      int R = wm + mi * 16 + lr, sw = R & 7;
      u16x8 a_r = *(const u16x8*)&sA[R][(lk ^ sw) * 8];
      u16x8 a_i = *(const u16x8*)&sA[R][((4 + lk) ^ sw) * 8];
      u16x8 na_i = a_i ^ sign8;
      for (int ni = 0; ni < 4; ++ni) {
        accre[mi][ni] = mfma_bf16(a_r, fWr[ni], accre[mi][ni]);
        accre[mi][ni] = mfma_bf16(na_i, fWi[ni], accre[mi][ni]);
        accim[mi][ni] = mfma_bf16(a_r, fWi[ni], accim[mi][ni]);
        accim[mi][ni] = mfma_bf16(a_i, fWr[ni], accim[mi][ni]);
      }
    }
    __syncthreads();
  }

  for (int ni = 0; ni < 4; ++ni) {
    int n = n0 + wn + ni * 16 + lr;
    float vbr = br[n], vbi = bi[n];
    for (int mi = 0; mi < 4; ++mi) {
      for (int r = 0; r < 4; ++r) {
        int m = m0 + wm + mi * 16 + lk * 4 + r;
        out[(size_t)m * 1024 + n] = accre[mi][ni][r] + vbr;
        out[8388608 + (size_t)m * 1024 + n] = accim[mi][ni][r] + vbi;
      }
    }
  }
}

// ---------------------------------------------------------------- launch
extern "C" void kernel_launch(void* const* d_in, const int* in_sizes, int n_in,
                              void* d_out, int out_size, void* d_ws, size_t ws_size,
                              hipStream_t stream) {
  const float* qre = (const float*)d_in[0];
  const float* qim = (const float*)d_in[1];
  const float* kre = (const float*)d_in[2];
  const float* kim = (const float*)d_in[3];
  const float* vre = (const float*)d_in[4];
  const float* vim = (const float*)d_in[5];
  const float* wqkv_re = (const float*)d_in[6];
  const float* wqkv_im = (const float*)d_in[7];
  const float* bqr = (const float*)d_in[8];
  const float* bqi = (const float*)d_in[9];
  const float* wo_re = (const float*)d_in[10];
  const float* wo_im = (const float*)d_in[11];
  const float* bor = (const float*)d_in[12];
  const float* boi = (const float*)d_in[13];

  char* ws = (char*)d_ws;
  unsigned short* wr_bf  = (unsigned short*)(ws + 0);          //  6.29 MB
  unsigned short* wi_bf  = (unsigned short*)(ws + 6291456);
  unsigned short* wor_bf = (unsigned short*)(ws + 12582912);
  unsigned short* woi_bf = (unsigned short*)(ws + 14680064);
  // activation bf16 (dead after proj_gemm)
  unsigned short* qreb   = (unsigned short*)(ws + 16777216);
  unsigned short* qimb   = (unsigned short*)(ws + 33554432);
  unsigned short* kreb   = (unsigned short*)(ws + 50331648);
  unsigned short* kimb   = (unsigned short*)(ws + 67108864);
  unsigned short* vreb   = (unsigned short*)(ws + 83886080);
  unsigned short* vimb   = (unsigned short*)(ws + 100663296);
  unsigned short* q2     = (unsigned short*)(ws + 117440512);  // 33.55 MB
  unsigned short* k2     = (unsigned short*)(ws + 150994944);
  unsigned short* vt     = (unsigned short*)(ws + 184549376);  // end 218.1 MB
  // attn outputs alias the dead activation region
  unsigned short* aor    = (unsigned short*)(ws + 16777216);
  unsigned short* aoi    = (unsigned short*)(ws + 33554432);

  cvt_kernel<<<3072, 256, 0, stream>>>(wqkv_re, wr_bf, 3145728);
  cvt_kernel<<<3072, 256, 0, stream>>>(wqkv_im, wi_bf, 3145728);
  cvt_kernel<<<1024, 256, 0, stream>>>(wo_re, wor_bf, 1048576);
  cvt_kernel<<<1024, 256, 0, stream>>>(wo_im, woi_bf, 1048576);
  cvt6_kernel<<<dim3(8192, 6), 256, 0, stream>>>(qre, qim, kre, kim, vre, vim,
                                                 qreb, qimb, kreb, kimb, vreb, vimb);

  proj_gemm<<<dim3(24, 64), 256, 0, stream>>>(qreb, qimb, kreb, kimb, vreb, vimb,
                                              wr_bf, wi_bf, bqr, bqi, q2, k2, vt);
  attn_kernel<<<1024, 256, 0, stream>>>(q2, k2, vt, aor, aoi);
  out_gemm<<<512, 256, 0, stream>>>(aor, aoi, wor_bf, woi_bf, bor, boi,
                                    (float*)d_out);
}

// Round 11
// 473.732 us; speedup vs baseline: 1.1453x; 1.0088x over previous
//
#include <hip/hip_runtime.h>

// Problem constants: S=1024, B=8, E=1024, H=16, HD=64
#define M_TOK 8192   // S*B
#define SEQ   1024
#define NB    8
#define EMB   1024
#define NH    16

typedef float  f32x4 __attribute__((ext_vector_type(4)));
typedef __bf16 bf16x8 __attribute__((ext_vector_type(8)));
typedef unsigned short u16x8 __attribute__((ext_vector_type(8)));
typedef unsigned short u16x4 __attribute__((ext_vector_type(4)));

__device__ __forceinline__ unsigned short f2bf(float f) {
  unsigned int u = __builtin_bit_cast(unsigned int, f);
  return (unsigned short)((u + 0x7fffu + ((u >> 16) & 1u)) >> 16);
}

__device__ __forceinline__ f32x4 mfma_bf16(u16x8 a, u16x8 b, f32x4 c) {
  return __builtin_amdgcn_mfma_f32_16x16x32_bf16(
      __builtin_bit_cast(bf16x8, a), __builtin_bit_cast(bf16x8, b), c, 0, 0, 0);
}

__device__ __forceinline__ void gload_lds16(const void* g, void* l) {
  __builtin_amdgcn_global_load_lds(
      (const __attribute__((address_space(1))) void*)g,
      (__attribute__((address_space(3))) void*)l, 16, 0, 0);
}

// ---------------------------------------------------------------- converts
// One fused kernel for all 10 f32->bf16 tensors. Flat grid, 1024 f32/block.
// Segments (in blocks): 6 x 8192 activations, 2 x 3072 wqkv, 2 x 1024 wo.
__global__ __launch_bounds__(256) void cvt_all(
    const float* __restrict__ aq, const float* __restrict__ aqi,
    const float* __restrict__ ak, const float* __restrict__ aki,
    const float* __restrict__ av, const float* __restrict__ avi,
    const float* __restrict__ wq, const float* __restrict__ wqi,
    const float* __restrict__ wo, const float* __restrict__ woi,
    unsigned short* __restrict__ dq, unsigned short* __restrict__ dqi,
    unsigned short* __restrict__ dk, unsigned short* __restrict__ dki,
    unsigned short* __restrict__ dv, unsigned short* __restrict__ dvi,
    unsigned short* __restrict__ dwq, unsigned short* __restrict__ dwqi,
    unsigned short* __restrict__ dwo, unsigned short* __restrict__ dwoi) {
  int b = blockIdx.x;
  const float* src;
  unsigned short* dst;
  int local;
  if (b < 49152) {
    int seg = b >> 13;
    local = b & 8191;
    src = (seg == 0) ? aq : (seg == 1) ? aqi : (seg == 2) ? ak
          : (seg == 3) ? aki : (seg == 4) ? av : avi;
    dst = (seg == 0) ? dq : (seg == 1) ? dqi : (seg == 2) ? dk
          : (seg == 3) ? dki : (seg == 4) ? dv : dvi;
  } else if (b < 52224) {
    src = wq; dst = dwq; local = b - 49152;
  } else if (b < 55296) {
    src = wqi; dst = dwqi; local = b - 52224;
  } else if (b < 56320) {
    src = wo; dst = dwo; local = b - 55296;
  } else {
    src = woi; dst = dwoi; local = b - 56320;
  }
  size_t off = (size_t)local * 1024 + threadIdx.x * 4;
  float4 v4 = *reinterpret_cast<const float4*>(src + off);
  u16x4 o = {f2bf(v4.x), f2bf(v4.y), f2bf(v4.z), f2bf(v4.w)};
  *reinterpret_cast<u16x4*>(dst + off) = o;
}

// ---------------------------------------------------------------- QKV proj
// (round-8 proven: 128x128 tile, combined [128][re32|im32] XOR-swizzled
// tiles, per-batch m-tiles, XCD swizzle 1536 = 8 x 192)
// q2 epilogue folds the attention scale 1/sqrt(64) (exact exponent shift).
__global__ __launch_bounds__(256, 2) void proj_gemm(
    const unsigned short* __restrict__ qreb, const unsigned short* __restrict__ qimb,
    const unsigned short* __restrict__ kreb, const unsigned short* __restrict__ kimb,
    const unsigned short* __restrict__ vreb, const unsigned short* __restrict__ vimb,
    const unsigned short* __restrict__ wr, const unsigned short* __restrict__ wi,
    const float* __restrict__ br, const float* __restrict__ bi,
    unsigned short* __restrict__ q2, unsigned short* __restrict__ k2,
    unsigned short* __restrict__ vt) {
  __shared__ __align__(16) unsigned short smem[18432];  // 36864 B
  unsigned short (*sA)[64] = (unsigned short (*)[64])(smem);          // [128][64]
  unsigned short (*sW)[64] = (unsigned short (*)[64])(smem + 8192);   // [128][64]
  unsigned short (*sC)[140]  = (unsigned short (*)[140])(smem);       // epilogue m-major
  unsigned short (*sCt)[144] = (unsigned short (*)[144])(smem);       // epilogue n-major

  const int tid = threadIdx.x;
  const int lane = tid & 63;
  const int w = tid >> 6;
  const int lr = lane & 15, lk = lane >> 4;
  const int wm = (w & 1) * 64, wn = (w >> 1) * 64;

  // XCD-aware bijective work swizzle: 1536 blocks = 8 XCD x 192
  const int lin = blockIdx.x + blockIdx.y * 24;
  const int wg = (lin & 7) * 192 + (lin >> 3);
  const int n0 = (wg % 24) * 128;
  const int mt = wg / 24;
  const int sec = n0 >> 10;
  const int bb = mt & 7;
  const int ss0 = (mt >> 3) * 128;
  const int h_base = (n0 & 1023) >> 6;

  const unsigned short* aRe = (sec == 0) ? qreb : ((sec == 1) ? kreb : vreb);
  const unsigned short* aIm = (sec == 0) ? qimb : ((sec == 1) ? kimb : vimb);

  int srow[4], sgsw[4];
  for (int c = 0; c < 4; ++c) {
    int gid = c * 256 + tid;
    srow[c] = gid >> 3;
    sgsw[c] = (gid & 7) ^ (srow[c] & 7);
  }

  f32x4 accre[4][4], accim[4][4];
  for (int i = 0; i < 4; ++i)
    for (int j = 0; j < 4; ++j) {
      accre[i][j] = {0.f, 0.f, 0.f, 0.f};
      accim[i][j] = {0.f, 0.f, 0.f, 0.f};
    }
  const u16x8 sign8 = {0x8000, 0x8000, 0x8000, 0x8000, 0x8000, 0x8000, 0x8000, 0x8000};

  for (int k0 = 0; k0 < 1024; k0 += 32) {
    for (int c = 0; c < 4; ++c) {
      int row = srow[c], gsw = sgsw[c];
      int kcol = k0 + (gsw & 3) * 8;
      size_t aoff = (size_t)((ss0 + row) * 8 + bb) * 1024 + kcol;
      gload_lds16((gsw < 4 ? aRe : aIm) + aoff, smem + (c * 256 + w * 64) * 8);
      size_t woff = (size_t)(n0 + row) * 1024 + kcol;
      gload_lds16((gsw < 4 ? wr : wi) + woff, smem + 8192 + (c * 256 + w * 64) * 8);
    }
    __syncthreads();

    u16x8 fWr[4], fWi[4];
    for (int ni = 0; ni < 4; ++ni) {
      int R = wn + ni * 16 + lr, sw = R & 7;
      fWr[ni] = *(const u16x8*)&sW[R][(lk ^ sw) * 8];
      fWi[ni] = *(const u16x8*)&sW[R][((4 + lk) ^ sw) * 8];
    }
    for (int mi = 0; mi < 4; ++mi) {
      int R = wm + mi * 16 + lr, sw = R & 7;
      u16x8 ar = *(const u16x8*)&sA[R][(lk ^ sw) * 8];
      u16x8 ai = *(const u16x8*)&sA[R][((4 + lk) ^ sw) * 8];
      u16x8 nai = ai ^ sign8;
      for (int ni = 0; ni < 4; ++ni) {
        accre[mi][ni] = mfma_bf16(ar, fWr[ni], accre[mi][ni]);
        accre[mi][ni] = mfma_bf16(nai, fWi[ni], accre[mi][ni]);
        accim[mi][ni] = mfma_bf16(ar, fWi[ni], accim[mi][ni]);
        accim[mi][ni] = mfma_bf16(ai, fWr[ni], accim[mi][ni]);
      }
    }
    __syncthreads();
  }

  float vbr[4], vbi[4];
  for (int ni = 0; ni < 4; ++ni) {
    int nabs = n0 + wn + ni * 16 + lr;
    vbr[ni] = br[nabs];
    vbi[ni] = bi[nabs];
  }
  // fold attention scale into q (exact: power-of-2 exponent shift)
  const float oscale = (sec == 0) ? 0.125f : 1.0f;

  if (sec < 2) {
    unsigned short* dst = (sec == 0) ? q2 : k2;
#define QK_PASS(ACC, BV, POFF)                                                  \
    for (int ni = 0; ni < 4; ++ni)                                              \
      for (int mi = 0; mi < 4; ++mi)                                            \
        for (int r = 0; r < 4; ++r)                                             \
          sC[wm + mi * 16 + lk * 4 + r][wn + ni * 16 + lr] =                    \
              f2bf((ACC[mi][ni][r] + BV[ni]) * oscale);                         \
    __syncthreads();                                                            \
    for (int it = 0; it < 8; ++it) {                                            \
      int c = it * 256 + tid;                                                   \
      int m = c >> 4, sub = c & 15, h_i = sub >> 3, d8 = sub & 7;               \
      u16x8 v = *(const u16x8*)&sC[m][h_i * 64 + d8 * 8];                       \
      size_t addr = ((size_t)((bb * 16 + h_base + h_i) * 1024 + ss0 + m)) * 128 \
                    + POFF + d8 * 8;                                            \
      *(u16x8*)(dst + addr) = v;                                                \
    }                                                                           \
    __syncthreads();
    QK_PASS(accre, vbr, 0)
    QK_PASS(accim, vbi, 64)
#undef QK_PASS
  } else {
#define VT_PASS(ACC, BV, POFF)                                                  \
    for (int ni = 0; ni < 4; ++ni)                                              \
      for (int mi = 0; mi < 4; ++mi)                                            \
        for (int r = 0; r < 4; ++r)                                             \
          sCt[wn + ni * 16 + lr][wm + mi * 16 + lk * 4 + r] =                   \
              f2bf(ACC[mi][ni][r] + BV[ni]);                                    \
    __syncthreads();                                                            \
    for (int it = 0; it < 8; ++it) {                                            \
      int c = it * 256 + tid;                                                   \
      int nl = c >> 4, sub = c & 15;                                            \
      int h_i = nl >> 6, d = nl & 63;                                           \
      u16x8 v = *(const u16x8*)&sCt[nl][sub * 8];                               \
      size_t addr = ((size_t)(bb * 16 + h_base + h_i) * 128 + d + POFF) * 1024  \
                    + ss0 + sub * 8;                                            \
      *(u16x8*)(vt + addr) = v;                                                 \
    }                                                                           \
    __syncthreads();
    VT_PASS(accre, vbr, 0)
    VT_PASS(accim, vbi, 64)
#undef VT_PASS
  }
}

// ---------------------------------------------------------------- attention
// 1D grid 1024, XCD-locality mapping. QBLK=128: 4 waves x 32 q-rows.
// Q in registers (pre-scaled by 1/8 at proj); single-buffer K/V (replay-proven
// sync); XOR-swizzled tiles; defer-max online softmax (THR=8).
__global__ __launch_bounds__(256, 2) void attn_kernel(
    const unsigned short* __restrict__ q2, const unsigned short* __restrict__ k2,
    const unsigned short* __restrict__ vt,
    unsigned short* __restrict__ aor, unsigned short* __restrict__ aoi) {
  __shared__ unsigned short sK[64][128];    // 16 KB
  __shared__ unsigned short sV[128][64];    // 16 KB
  __shared__ unsigned short sP[4][32][72];  // 18 KB, +8 pad

  const int tid = threadIdx.x, lane = tid & 63, w = tid >> 6;
  const int lr = lane & 15, lk = lane >> 4;
  const int lin = blockIdx.x;
  const int idx = lin >> 3;                    // 0..127
  const int bh = (lin & 7) * 16 + (idx >> 3);  // XCD-local bh
  const int q0 = (idx & 7) * 128;
  const int bb = bh >> 4, hh = bh & 15;

  const unsigned short* kbase = k2 + (size_t)bh * 131072;
  const unsigned short* vbase = vt + (size_t)bh * 131072;

  // Q fragments in registers (32 VGPRs), read once
  u16x8 qf[2][4];
#pragma unroll
  for (int fi = 0; fi < 2; ++fi) {
    int row = q0 + w * 32 + fi * 16 + lr;
#pragma unroll
    for (int ks = 0; ks < 4; ++ks)
      qf[fi][ks] = *(const u16x8*)(q2 + (size_t)bh * 131072 + (size_t)row * 128 +
                                   ks * 32 + lk * 8);
  }

  f32x4 o[2][8];
#pragma unroll
  for (int fi = 0; fi < 2; ++fi)
#pragma unroll
    for (int i = 0; i < 8; ++i) o[fi][i] = {0.f, 0.f, 0.f, 0.f};
  float mrun[2][4], lrun[2][4];
#pragma unroll
  for (int fi = 0; fi < 2; ++fi)
#pragma unroll
    for (int r = 0; r < 4; ++r) {
      mrun[fi][r] = -1e30f;
      lrun[fi][r] = 0.f;
    }

#pragma unroll 1
  for (int t0 = 0; t0 < 1024; t0 += 64) {
    // stage K tile (64 x 128), swizzled source
    const unsigned short* kb = kbase + (size_t)t0 * 128;
#pragma unroll
    for (int c = 0; c < 4; ++c) {
      int rb = (w * 4 + c) * 4;
      int row = rb + (lane >> 4);
      int blk = (lane & 15) ^ (row & 7);
      gload_lds16(kb + (size_t)row * 128 + blk * 8, &sK[rb][0]);
    }
    // stage V tile (128 x 64), swizzled source
    const unsigned short* vb = vbase + t0;
#pragma unroll
    for (int c = 0; c < 4; ++c) {
      int rb = (w * 4 + c) * 8;
      int row = rb + (lane >> 3);
      int blk = (lane & 7) ^ (row & 7);
      gload_lds16(vb + (size_t)row * 1024 + blk * 8, &sV[rb][0]);
    }
    __syncthreads();

#pragma unroll
    for (int fi = 0; fi < 2; ++fi) {
      // scores: this frag's 16 q-rows x 64 t (Q pre-scaled by 1/8)
      f32x4 sc[4];
#pragma unroll
      for (int nj = 0; nj < 4; ++nj) sc[nj] = {0.f, 0.f, 0.f, 0.f};
      __builtin_amdgcn_s_setprio(1);
#pragma unroll
      for (int ks = 0; ks < 4; ++ks) {
#pragma unroll
        for (int nj = 0; nj < 4; ++nj) {
          int krow = nj * 16 + lr;
          u16x8 kf = *(const u16x8*)&sK[krow][((ks * 4 + lk) ^ (krow & 7)) * 8];
          sc[nj] = mfma_bf16(qf[fi][ks], kf, sc[nj]);
        }
      }
      __builtin_amdgcn_s_setprio(0);

      // tile max per row + defer decision
      float pmx[4];
      bool need = false;
#pragma unroll
      for (int r = 0; r < 4; ++r) {
        float mx = fmaxf(fmaxf(sc[0][r], sc[1][r]), fmaxf(sc[2][r], sc[3][r]));
        for (int msk = 1; msk < 16; msk <<= 1) mx = fmaxf(mx, __shfl_xor(mx, msk));
        pmx[r] = mx;
        need = need || (mx > mrun[fi][r] + 8.0f);
      }

      if (__any(need)) {
        // full online-softmax update
#pragma unroll
        for (int r = 0; r < 4; ++r) {
          float mnew = fmaxf(mrun[fi][r], pmx[r]);
          float corr = __expf(mrun[fi][r] - mnew);
          float p0 = __expf(sc[0][r] - mnew), p1 = __expf(sc[1][r] - mnew);
          float p2 = __expf(sc[2][r] - mnew), p3 = __expf(sc[3][r] - mnew);
          float rs = p0 + p1 + p2 + p3;
          for (int msk = 1; msk < 16; msk <<= 1) rs += __shfl_xor(rs, msk);
          lrun[fi][r] = lrun[fi][r] * corr + rs;
          mrun[fi][r] = mnew;
#pragma unroll
          for (int ni = 0; ni < 8; ++ni) o[fi][ni][r] *= corr;
          int prow = fi * 16 + lk * 4 + r;
          sP[w][prow][0 * 16 + lr] = f2bf(p0);
          sP[w][prow][1 * 16 + lr] = f2bf(p1);
          sP[w][prow][2 * 16 + lr] = f2bf(p2);
          sP[w][prow][3 * 16 + lr] = f2bf(p3);
        }
      } else {
        // deferred: keep old max, no rescale (P bounded by e^8)
#pragma unroll
        for (int r = 0; r < 4; ++r) {
          float m = mrun[fi][r];
          float p0 = __expf(sc[0][r] - m), p1 = __expf(sc[1][r] - m);
          float p2 = __expf(sc[2][r] - m), p3 = __expf(sc[3][r] - m);
          float rs = p0 + p1 + p2 + p3;
          for (int msk = 1; msk < 16; msk <<= 1) rs += __shfl_xor(rs, msk);
          lrun[fi][r] += rs;
          int prow = fi * 16 + lk * 4 + r;
          sP[w][prow][0 * 16 + lr] = f2bf(p0);
          sP[w][prow][1 * 16 + lr] = f2bf(p1);
          sP[w][prow][2 * 16 + lr] = f2bf(p2);
          sP[w][prow][3 * 16 + lr] = f2bf(p3);
        }
      }
    }

    // PV: O[s, dd] += P[s, t] * VT[dd, t]  (V fragments shared across fi)
    __builtin_amdgcn_s_setprio(1);
#pragma unroll
    for (int ks = 0; ks < 2; ++ks) {
      u16x8 pf0 = *(const u16x8*)&sP[w][lr][ks * 32 + lk * 8];
      u16x8 pf1 = *(const u16x8*)&sP[w][16 + lr][ks * 32 + lk * 8];
#pragma unroll
      for (int ni = 0; ni < 8; ++ni) {
        int vrow = ni * 16 + lr;
        u16x8 vf = *(const u16x8*)&sV[vrow][((ks * 4 + lk) ^ (vrow & 7)) * 8];
        o[0][ni] = mfma_bf16(pf0, vf, o[0][ni]);
        o[1][ni] = mfma_bf16(pf1, vf, o[1][ni]);
      }
    }
    __builtin_amdgcn_s_setprio(0);
    __syncthreads();
  }

#pragma unroll
  for (int fi = 0; fi < 2; ++fi)
#pragma unroll
    for (int r = 0; r < 4; ++r) {
      float inv = 1.0f / lrun[fi][r];
#pragma unroll
      for (int ni = 0; ni < 8; ++ni) o[fi][ni][r] *= inv;
    }
#pragma unroll
  for (int fi = 0; fi < 2; ++fi)
#pragma unroll
    for (int ni = 0; ni < 8; ++ni) {
      int dd = ni * 16 + lr;
#pragma unroll
      for (int r = 0; r < 4; ++r) {
        int sg = q0 + w * 32 + fi * 16 + lk * 4 + r;
        size_t tok = (size_t)sg * 8 + bb;
        if (dd < 64)
          aor[tok * 1024 + hh * 64 + dd] = f2bf(o[fi][ni][r]);
        else
          aoi[tok * 1024 + hh * 64 + (dd - 64)] = f2bf(o[fi][ni][r]);
      }
    }
}

// ---------------------------------------------------------------- out proj
// (round-8 proven: combined [128][re32|im32] XOR-swizzled tiles; XCD swizzle)
__global__ __launch_bounds__(256, 2) void out_gemm(
    const unsigned short* __restrict__ ar, const unsigned short* __restrict__ ai,
    const unsigned short* __restrict__ wr, const unsigned short* __restrict__ wi,
    const float* __restrict__ br, const float* __restrict__ bi,
    float* __restrict__ out) {
  __shared__ __align__(16) unsigned short smem[16384];  // 32 KB
  unsigned short (*sA)[64] = (unsigned short (*)[64])(smem);
  unsigned short (*sW)[64] = (unsigned short (*)[64])(smem + 8192);

  const int tid = threadIdx.x;
  const int lane = tid & 63;
  const int w = tid >> 6;
  const int lr = lane & 15, lk = lane >> 4;
  const int wm = (w & 1) * 64, wn = (w >> 1) * 64;

  const int lin = blockIdx.x;
  const int wg = (lin & 7) * 64 + (lin >> 3);
  const int n0 = (wg & 7) * 128;
  const int m0 = (wg >> 3) * 128;

  int srow[4], sgsw[4];
  for (int c = 0; c < 4; ++c) {
    int gid = c * 256 + tid;
    srow[c] = gid >> 3;
    sgsw[c] = (gid & 7) ^ (srow[c] & 7);
  }

  f32x4 accre[4][4], accim[4][4];
  for (int i = 0; i < 4; ++i)
    for (int j = 0; j < 4; ++j) {
      accre[i][j] = {0.f, 0.f, 0.f, 0.f};
      accim[i][j] = {0.f, 0.f, 0.f, 0.f};
    }
  const u16x8 sign8 = {0x8000, 0x8000, 0x8000, 0x8000, 0x8000, 0x8000, 0x8000, 0x8000};

  for (int k0 = 0; k0 < 1024; k0 += 32) {
    for (int c = 0; c < 4; ++c) {
      int row = srow[c], gsw = sgsw[c];
      int kcol = k0 + (gsw & 3) * 8;
      size_t aoff = (size_t)(m0 + row) * 1024 + kcol;
      gload_lds16((gsw < 4 ? ar : ai) + aoff, smem + (c * 256 + w * 64) * 8);
      size_t woff = (size_t)(n0 + row) * 1024 + kcol;
      gload_lds16((gsw < 4 ? wr : wi) + woff, smem + 8192 + (c * 256 + w * 64) * 8);
    }
    __syncthreads();

    u16x8 fWr[4], fWi[4];
    for (int ni = 0; ni < 4; ++ni) {
      int R = wn + ni * 16 + lr, sw = R & 7;
      fWr[ni] = *(const u16x8*)&sW[R][(lk ^ sw) * 8];
      fWi[ni] = *(const u16x8*)&sW[R][((4 + lk) ^ sw) * 8];
    }
    for (int mi = 0; mi < 4; ++mi) {
      int R = wm + mi * 16 + lr, sw = R & 7;
      u16x8 a_r = *(const u16x8*)&sA[R][(lk ^ sw) * 8];
      u16x8 a_i = *(const u16x8*)&sA[R][((4 + lk) ^ sw) * 8];
      u16x8 na_i = a_i ^ sign8;
      for (int ni = 0; ni < 4; ++ni) {
        accre[mi][ni] = mfma_bf16(a_r, fWr[ni], accre[mi][ni]);
        accre[mi][ni] = mfma_bf16(na_i, fWi[ni], accre[mi][ni]);
        accim[mi][ni] = mfma_bf16(a_r, fWi[ni], accim[mi][ni]);
        accim[mi][ni] = mfma_bf16(a_i, fWr[ni], accim[mi][ni]);
      }
    }
    __syncthreads();
  }

  for (int ni = 0; ni < 4; ++ni) {
    int n = n0 + wn + ni * 16 + lr;
    float vbr = br[n], vbi = bi[n];
    for (int mi = 0; mi < 4; ++mi) {
      for (int r = 0; r < 4; ++r) {
        int m = m0 + wm + mi * 16 + lk * 4 + r;
        out[(size_t)m * 1024 + n] = accre[mi][ni][r] + vbr;
        out[8388608 + (size_t)m * 1024 + n] = accim[mi][ni][r] + vbi;
      }
    }
  }
}

// ---------------------------------------------------------------- launch
extern "C" void kernel_launch(void* const* d_in, const int* in_sizes, int n_in,
                              void* d_out, int out_size, void* d_ws, size_t ws_size,
                              hipStream_t stream) {
  const float* qre = (const float*)d_in[0];
  const float* qim = (const float*)d_in[1];
  const float* kre = (const float*)d_in[2];
  const float* kim = (const float*)d_in[3];
  const float* vre = (const float*)d_in[4];
  const float* vim = (const float*)d_in[5];
  const float* wqkv_re = (const float*)d_in[6];
  const float* wqkv_im = (const float*)d_in[7];
  const float* bqr = (const float*)d_in[8];
  const float* bqi = (const float*)d_in[9];
  const float* wo_re = (const float*)d_in[10];
  const float* wo_im = (const float*)d_in[11];
  const float* bor = (const float*)d_in[12];
  const float* boi = (const float*)d_in[13];

  char* ws = (char*)d_ws;
  unsigned short* wr_bf  = (unsigned short*)(ws + 0);          //  6.29 MB
  unsigned short* wi_bf  = (unsigned short*)(ws + 6291456);
  unsigned short* wor_bf = (unsigned short*)(ws + 12582912);
  unsigned short* woi_bf = (unsigned short*)(ws + 14680064);
  // activation bf16 (dead after proj_gemm)
  unsigned short* qreb   = (unsigned short*)(ws + 16777216);
  unsigned short* qimb   = (unsigned short*)(ws + 33554432);
  unsigned short* kreb   = (unsigned short*)(ws + 50331648);
  unsigned short* kimb   = (unsigned short*)(ws + 67108864);
  unsigned short* vreb   = (unsigned short*)(ws + 83886080);
  unsigned short* vimb   = (unsigned short*)(ws + 100663296);
  unsigned short* q2     = (unsigned short*)(ws + 117440512);  // 33.55 MB
  unsigned short* k2     = (unsigned short*)(ws + 150994944);
  unsigned short* vt     = (unsigned short*)(ws + 184549376);  // end 218.1 MB
  // attn outputs alias the dead activation region
  unsigned short* aor    = (unsigned short*)(ws + 16777216);
  unsigned short* aoi    = (unsigned short*)(ws + 33554432);

  cvt_all<<<57344, 256, 0, stream>>>(qre, qim, kre, kim, vre, vim,
                                     wqkv_re, wqkv_im, wo_re, wo_im,
                                     qreb, qimb, kreb, kimb, vreb, vimb,
                                     wr_bf, wi_bf, wor_bf, woi_bf);

  proj_gemm<<<dim3(24, 64), 256, 0, stream>>>(qreb, qimb, kreb, kimb, vreb, vimb,
                                              wr_bf, wi_bf, bqr, bqi, q2, k2, vt);
  attn_kernel<<<1024, 256, 0, stream>>>(q2, k2, vt, aor, aoi);
  out_gemm<<<512, 256, 0, stream>>>(aor, aoi, wor_bf, woi_bf, bor, boi,
                                    (float*)d_out);
}

// Round 12
// 466.305 us; speedup vs baseline: 1.1635x; 1.0159x over previous
//
#include <hip/hip_runtime.h>

// Problem constants: S=1024, B=8, E=1024, H=16, HD=64
#define M_TOK 8192   // S*B
#define SEQ   1024
#define NB    8
#define EMB   1024
#define NH    16

typedef float  f32x4 __attribute__((ext_vector_type(4)));
typedef __bf16 bf16x8 __attribute__((ext_vector_type(8)));
typedef unsigned short u16x8 __attribute__((ext_vector_type(8)));
typedef unsigned short u16x4 __attribute__((ext_vector_type(4)));

__device__ __forceinline__ unsigned short f2bf(float f) {
  unsigned int u = __builtin_bit_cast(unsigned int, f);
  return (unsigned short)((u + 0x7fffu + ((u >> 16) & 1u)) >> 16);
}

__device__ __forceinline__ f32x4 mfma_bf16(u16x8 a, u16x8 b, f32x4 c) {
  return __builtin_amdgcn_mfma_f32_16x16x32_bf16(
      __builtin_bit_cast(bf16x8, a), __builtin_bit_cast(bf16x8, b), c, 0, 0, 0);
}

__device__ __forceinline__ void gload_lds16(const void* g, void* l) {
  __builtin_amdgcn_global_load_lds(
      (const __attribute__((address_space(1))) void*)g,
      (__attribute__((address_space(3))) void*)l, 16, 0, 0);
}

// ---------------------------------------------------------------- converts
// Fused convert. Activations -> K-tiled batch-major bf16:
//   act'[k>>5][mp][k&31], mp = b*1024 + s   (one MFMA A-frag = 1KB contiguous)
// Weights -> linear bf16.
// Grid: 6*2048 activation blocks (4 rows each) + 8192 weight blocks (1024 f32).
__global__ __launch_bounds__(256) void cvt_all(
    const float* __restrict__ aq, const float* __restrict__ aqi,
    const float* __restrict__ ak, const float* __restrict__ aki,
    const float* __restrict__ av, const float* __restrict__ avi,
    const float* __restrict__ wq, const float* __restrict__ wqi,
    const float* __restrict__ wo, const float* __restrict__ woi,
    unsigned short* __restrict__ dq, unsigned short* __restrict__ dqi,
    unsigned short* __restrict__ dk, unsigned short* __restrict__ dki,
    unsigned short* __restrict__ dv, unsigned short* __restrict__ dvi,
    unsigned short* __restrict__ dwq, unsigned short* __restrict__ dwqi,
    unsigned short* __restrict__ dwo, unsigned short* __restrict__ dwoi) {
  int b = blockIdx.x;
  if (b < 12288) {
    int seg = b >> 11, local = b & 2047;
    const float* src = (seg == 0) ? aq : (seg == 1) ? aqi : (seg == 2) ? ak
                       : (seg == 3) ? aki : (seg == 4) ? av : avi;
    unsigned short* dst = (seg == 0) ? dq : (seg == 1) ? dqi : (seg == 2) ? dk
                          : (seg == 3) ? dki : (seg == 4) ? dv : dvi;
    int mp0 = local * 4;                 // 4 consecutive m' (same batch)
    int bidx = mp0 >> 10, s0 = mp0 & 1023;
    int rr = threadIdx.x >> 6, tt = threadIdx.x & 63;
    const float* srow = src + (size_t)((s0 + rr) * 8 + bidx) * 1024 + tt * 16;
    float4 v0 = ((const float4*)srow)[0];
    float4 v1 = ((const float4*)srow)[1];
    float4 v2 = ((const float4*)srow)[2];
    float4 v3 = ((const float4*)srow)[3];
    u16x8 o0 = {f2bf(v0.x), f2bf(v0.y), f2bf(v0.z), f2bf(v0.w),
                f2bf(v1.x), f2bf(v1.y), f2bf(v1.z), f2bf(v1.w)};
    u16x8 o1 = {f2bf(v2.x), f2bf(v2.y), f2bf(v2.z), f2bf(v2.w),
                f2bf(v3.x), f2bf(v3.y), f2bf(v3.z), f2bf(v3.w)};
    unsigned short* d = dst + (size_t)(tt >> 1) * 262144 +
                        (size_t)(mp0 + rr) * 32 + (tt & 1) * 16;
    *(u16x8*)d = o0;
    *(u16x8*)(d + 8) = o1;
  } else {
    int b2 = b - 12288;
    const float* src;
    unsigned short* dst;
    int local;
    if (b2 < 3072) { src = wq; dst = dwq; local = b2; }
    else if (b2 < 6144) { src = wqi; dst = dwqi; local = b2 - 3072; }
    else if (b2 < 7168) { src = wo; dst = dwo; local = b2 - 6144; }
    else { src = woi; dst = dwoi; local = b2 - 7168; }
    size_t off = (size_t)local * 1024 + threadIdx.x * 4;
    float4 v4 = *reinterpret_cast<const float4*>(src + off);
    u16x4 o = {f2bf(v4.x), f2bf(v4.y), f2bf(v4.z), f2bf(v4.w)};
    *reinterpret_cast<u16x4*>(dst + off) = o;
  }
}

// ---------------------------------------------------------------- QKV proj
// 128x128 tile. A-frags loaded DIRECT from K-tiled global layout (1KB
// coalesced per frag, L2-served) -> LDS holds W only (halves LDS traffic,
// which was the measured 42%-MfmaUtil bound). W via gload_lds, XOR-swizzled
// [128][re32|im32]. Batch-major m' tiles; XCD swizzle 1536 = 8x192.
// q2 epilogue folds the attention scale 1/8 (exact exponent shift).
__global__ __launch_bounds__(256, 2) void proj_gemm(
    const unsigned short* __restrict__ qreb, const unsigned short* __restrict__ qimb,
    const unsigned short* __restrict__ kreb, const unsigned short* __restrict__ kimb,
    const unsigned short* __restrict__ vreb, const unsigned short* __restrict__ vimb,
    const unsigned short* __restrict__ wr, const unsigned short* __restrict__ wi,
    const float* __restrict__ br, const float* __restrict__ bi,
    unsigned short* __restrict__ q2, unsigned short* __restrict__ k2,
    unsigned short* __restrict__ vt) {
  __shared__ __align__(16) unsigned short smem[18432];  // 36864 B (epilogue reuse)
  unsigned short (*sW)[64] = (unsigned short (*)[64])(smem);          // [128][64]
  unsigned short (*sC)[140]  = (unsigned short (*)[140])(smem);       // epilogue m-major
  unsigned short (*sCt)[144] = (unsigned short (*)[144])(smem);       // epilogue n-major

  const int tid = threadIdx.x;
  const int lane = tid & 63;
  const int w = tid >> 6;
  const int lr = lane & 15, lk = lane >> 4;
  const int wm = (w & 1) * 64, wn = (w >> 1) * 64;

  // XCD-aware bijective work swizzle: 1536 blocks = 8 XCD x 192
  const int lin = blockIdx.x + blockIdx.y * 24;
  const int wg = (lin & 7) * 192 + (lin >> 3);
  const int n0 = (wg % 24) * 128;
  const int mt = wg / 24;
  const int sec = n0 >> 10;
  const int bb = mt >> 3;            // batch (batch-major m')
  const int ss0 = (mt & 7) * 128;    // s-offset
  const int h_base = (n0 & 1023) >> 6;

  const unsigned short* aRe = (sec == 0) ? qreb : ((sec == 1) ? kreb : vreb);
  const unsigned short* aIm = (sec == 0) ? qimb : ((sec == 1) ? kimb : vimb);

  // W staging indices (granule gid = c*256+tid; row = gid>>3; g = gid&7)
  int srow[4], sgsw[4];
  for (int c = 0; c < 4; ++c) {
    int gid = c * 256 + tid;
    srow[c] = gid >> 3;
    sgsw[c] = (gid & 7) ^ (srow[c] & 7);
  }

  // A-frag offset in tiled layout: frag(mi) = 1KB contiguous block
  const unsigned int aoff = (unsigned int)((mt * 128 + wm + lr) * 32 + lk * 8);

  f32x4 accre[4][4], accim[4][4];
  for (int i = 0; i < 4; ++i)
    for (int j = 0; j < 4; ++j) {
      accre[i][j] = {0.f, 0.f, 0.f, 0.f};
      accim[i][j] = {0.f, 0.f, 0.f, 0.f};
    }
  const u16x8 sign8 = {0x8000, 0x8000, 0x8000, 0x8000, 0x8000, 0x8000, 0x8000, 0x8000};

#pragma unroll 1
  for (int k0 = 0; k0 < 1024; k0 += 32) {
    const unsigned short* paR = aRe + (size_t)(k0 >> 5) * 262144;
    const unsigned short* paI = aIm + (size_t)(k0 >> 5) * 262144;
    u16x8 ar_[4], ai_[4];
#pragma unroll
    for (int mi = 0; mi < 4; ++mi) {
      ar_[mi] = *(const u16x8*)(paR + aoff + mi * 512);
      ai_[mi] = *(const u16x8*)(paI + aoff + mi * 512);
    }
    // W staging (async to LDS); barrier drains both A loads and W stores
#pragma unroll
    for (int c = 0; c < 4; ++c) {
      int row = srow[c], gsw = sgsw[c];
      int kcol = k0 + (gsw & 3) * 8;
      size_t woff = (size_t)(n0 + row) * 1024 + kcol;
      gload_lds16((gsw < 4 ? wr : wi) + woff, smem + (c * 256 + w * 64) * 8);
    }
    __syncthreads();

    u16x8 fWr[4], fWi[4];
#pragma unroll
    for (int ni = 0; ni < 4; ++ni) {
      int R = wn + ni * 16 + lr, sw = R & 7;
      fWr[ni] = *(const u16x8*)&sW[R][(lk ^ sw) * 8];
      fWi[ni] = *(const u16x8*)&sW[R][((4 + lk) ^ sw) * 8];
    }
#pragma unroll
    for (int mi = 0; mi < 4; ++mi) {
      u16x8 nai = ai_[mi] ^ sign8;
#pragma unroll
      for (int ni = 0; ni < 4; ++ni) {
        accre[mi][ni] = mfma_bf16(ar_[mi], fWr[ni], accre[mi][ni]);
        accre[mi][ni] = mfma_bf16(nai, fWi[ni], accre[mi][ni]);
        accim[mi][ni] = mfma_bf16(ar_[mi], fWi[ni], accim[mi][ni]);
        accim[mi][ni] = mfma_bf16(ai_[mi], fWr[ni], accim[mi][ni]);
      }
    }
    __syncthreads();
  }

  float vbr[4], vbi[4];
  for (int ni = 0; ni < 4; ++ni) {
    int nabs = n0 + wn + ni * 16 + lr;
    vbr[ni] = br[nabs];
    vbi[ni] = bi[nabs];
  }
  // fold attention scale into q (exact: power-of-2 exponent shift)
  const float oscale = (sec == 0) ? 0.125f : 1.0f;

  if (sec < 2) {
    unsigned short* dst = (sec == 0) ? q2 : k2;
#define QK_PASS(ACC, BV, POFF)                                                  \
    for (int ni = 0; ni < 4; ++ni)                                              \
      for (int mi = 0; mi < 4; ++mi)                                            \
        for (int r = 0; r < 4; ++r)                                             \
          sC[wm + mi * 16 + lk * 4 + r][wn + ni * 16 + lr] =                    \
              f2bf((ACC[mi][ni][r] + BV[ni]) * oscale);                         \
    __syncthreads();                                                            \
    for (int it = 0; it < 8; ++it) {                                            \
      int c = it * 256 + tid;                                                   \
      int m = c >> 4, sub = c & 15, h_i = sub >> 3, d8 = sub & 7;               \
      u16x8 v = *(const u16x8*)&sC[m][h_i * 64 + d8 * 8];                       \
      size_t addr = ((size_t)((bb * 16 + h_base + h_i) * 1024 + ss0 + m)) * 128 \
                    + POFF + d8 * 8;                                            \
      *(u16x8*)(dst + addr) = v;                                                \
    }                                                                           \
    __syncthreads();
    QK_PASS(accre, vbr, 0)
    QK_PASS(accim, vbi, 64)
#undef QK_PASS
  } else {
#define VT_PASS(ACC, BV, POFF)                                                  \
    for (int ni = 0; ni < 4; ++ni)                                              \
      for (int mi = 0; mi < 4; ++mi)                                            \
        for (int r = 0; r < 4; ++r)                                             \
          sCt[wn + ni * 16 + lr][wm + mi * 16 + lk * 4 + r] =                   \
              f2bf(ACC[mi][ni][r] + BV[ni]);                                    \
    __syncthreads();                                                            \
    for (int it = 0; it < 8; ++it) {                                            \
      int c = it * 256 + tid;                                                   \
      int nl = c >> 4, sub = c & 15;                                            \
      int h_i = nl >> 6, d = nl & 63;                                           \
      u16x8 v = *(const u16x8*)&sCt[nl][sub * 8];                               \
      size_t addr = ((size_t)(bb * 16 + h_base + h_i) * 128 + d + POFF) * 1024  \
                    + ss0 + sub * 8;                                            \
      *(u16x8*)(vt + addr) = v;                                                 \
    }                                                                           \
    __syncthreads();
    VT_PASS(accre, vbr, 0)
    VT_PASS(accim, vbi, 64)
#undef VT_PASS
  }
}

// ---------------------------------------------------------------- attention
// 1D grid 1024, XCD-locality mapping. QBLK=128: 4 waves x 32 q-rows.
// Q in registers (pre-scaled 1/8); single-buffer K/V (replay-proven sync);
// XOR-swizzled tiles; defer-max softmax (THR=8). K-fragments read ONCE and
// shared across both q-row groups (halves QK^T LDS reads).
__global__ __launch_bounds__(256, 2) void attn_kernel(
    const unsigned short* __restrict__ q2, const unsigned short* __restrict__ k2,
    const unsigned short* __restrict__ vt,
    unsigned short* __restrict__ aor, unsigned short* __restrict__ aoi) {
  __shared__ unsigned short sK[64][128];    // 16 KB
  __shared__ unsigned short sV[128][64];    // 16 KB
  __shared__ unsigned short sP[4][32][72];  // 18 KB, +8 pad

  const int tid = threadIdx.x, lane = tid & 63, w = tid >> 6;
  const int lr = lane & 15, lk = lane >> 4;
  const int lin = blockIdx.x;
  const int idx = lin >> 3;                    // 0..127
  const int bh = (lin & 7) * 16 + (idx >> 3);  // XCD-local bh
  const int q0 = (idx & 7) * 128;
  const int bb = bh >> 4, hh = bh & 15;

  const unsigned short* kbase = k2 + (size_t)bh * 131072;
  const unsigned short* vbase = vt + (size_t)bh * 131072;

  // Q fragments in registers (32 VGPRs), read once
  u16x8 qf[2][4];
#pragma unroll
  for (int fi = 0; fi < 2; ++fi) {
    int row = q0 + w * 32 + fi * 16 + lr;
#pragma unroll
    for (int ks = 0; ks < 4; ++ks)
      qf[fi][ks] = *(const u16x8*)(q2 + (size_t)bh * 131072 + (size_t)row * 128 +
                                   ks * 32 + lk * 8);
  }

  f32x4 o[2][8];
#pragma unroll
  for (int fi = 0; fi < 2; ++fi)
#pragma unroll
    for (int i = 0; i < 8; ++i) o[fi][i] = {0.f, 0.f, 0.f, 0.f};
  float mrun[2][4], lrun[2][4];
#pragma unroll
  for (int fi = 0; fi < 2; ++fi)
#pragma unroll
    for (int r = 0; r < 4; ++r) {
      mrun[fi][r] = -1e30f;
      lrun[fi][r] = 0.f;
    }

#pragma unroll 1
  for (int t0 = 0; t0 < 1024; t0 += 64) {
    // stage K tile (64 x 128), swizzled source
    const unsigned short* kb = kbase + (size_t)t0 * 128;
#pragma unroll
    for (int c = 0; c < 4; ++c) {
      int rb = (w * 4 + c) * 4;
      int row = rb + (lane >> 4);
      int blk = (lane & 15) ^ (row & 7);
      gload_lds16(kb + (size_t)row * 128 + blk * 8, &sK[rb][0]);
    }
    // stage V tile (128 x 64), swizzled source
    const unsigned short* vb = vbase + t0;
#pragma unroll
    for (int c = 0; c < 4; ++c) {
      int rb = (w * 4 + c) * 8;
      int row = rb + (lane >> 3);
      int blk = (lane & 7) ^ (row & 7);
      gload_lds16(vb + (size_t)row * 1024 + blk * 8, &sV[rb][0]);
    }
    __syncthreads();

    // QK^T for BOTH q-row groups, each K-fragment read once
    f32x4 sc[2][4];
#pragma unroll
    for (int fi = 0; fi < 2; ++fi)
#pragma unroll
      for (int nj = 0; nj < 4; ++nj) sc[fi][nj] = {0.f, 0.f, 0.f, 0.f};
    __builtin_amdgcn_s_setprio(1);
#pragma unroll
    for (int ks = 0; ks < 4; ++ks) {
#pragma unroll
      for (int nj = 0; nj < 4; ++nj) {
        int krow = nj * 16 + lr;
        u16x8 kf = *(const u16x8*)&sK[krow][((ks * 4 + lk) ^ (krow & 7)) * 8];
        sc[0][nj] = mfma_bf16(qf[0][ks], kf, sc[0][nj]);
        sc[1][nj] = mfma_bf16(qf[1][ks], kf, sc[1][nj]);
      }
    }
    __builtin_amdgcn_s_setprio(0);

#pragma unroll
    for (int fi = 0; fi < 2; ++fi) {
      // tile max per row + defer decision
      float pmx[4];
      bool need = false;
#pragma unroll
      for (int r = 0; r < 4; ++r) {
        float mx = fmaxf(fmaxf(sc[fi][0][r], sc[fi][1][r]),
                         fmaxf(sc[fi][2][r], sc[fi][3][r]));
        for (int msk = 1; msk < 16; msk <<= 1) mx = fmaxf(mx, __shfl_xor(mx, msk));
        pmx[r] = mx;
        need = need || (mx > mrun[fi][r] + 8.0f);
      }

      if (__any(need)) {
        // full online-softmax update
#pragma unroll
        for (int r = 0; r < 4; ++r) {
          float mnew = fmaxf(mrun[fi][r], pmx[r]);
          float corr = __expf(mrun[fi][r] - mnew);
          float p0 = __expf(sc[fi][0][r] - mnew), p1 = __expf(sc[fi][1][r] - mnew);
          float p2 = __expf(sc[fi][2][r] - mnew), p3 = __expf(sc[fi][3][r] - mnew);
          float rs = p0 + p1 + p2 + p3;
          for (int msk = 1; msk < 16; msk <<= 1) rs += __shfl_xor(rs, msk);
          lrun[fi][r] = lrun[fi][r] * corr + rs;
          mrun[fi][r] = mnew;
#pragma unroll
          for (int ni = 0; ni < 8; ++ni) o[fi][ni][r] *= corr;
          int prow = fi * 16 + lk * 4 + r;
          sP[w][prow][0 * 16 + lr] = f2bf(p0);
          sP[w][prow][1 * 16 + lr] = f2bf(p1);
          sP[w][prow][2 * 16 + lr] = f2bf(p2);
          sP[w][prow][3 * 16 + lr] = f2bf(p3);
        }
      } else {
        // deferred: keep old max, no rescale (P bounded by e^8)
#pragma unroll
        for (int r = 0; r < 4; ++r) {
          float m = mrun[fi][r];
          float p0 = __expf(sc[fi][0][r] - m), p1 = __expf(sc[fi][1][r] - m);
          float p2 = __expf(sc[fi][2][r] - m), p3 = __expf(sc[fi][3][r] - m);
          float rs = p0 + p1 + p2 + p3;
          for (int msk = 1; msk < 16; msk <<= 1) rs += __shfl_xor(rs, msk);
          lrun[fi][r] += rs;
          int prow = fi * 16 + lk * 4 + r;
          sP[w][prow][0 * 16 + lr] = f2bf(p0);
          sP[w][prow][1 * 16 + lr] = f2bf(p1);
          sP[w][prow][2 * 16 + lr] = f2bf(p2);
          sP[w][prow][3 * 16 + lr] = f2bf(p3);
        }
      }
    }

    // PV: O[s, dd] += P[s, t] * VT[dd, t]  (V fragments shared across fi)
    __builtin_amdgcn_s_setprio(1);
#pragma unroll
    for (int ks = 0; ks < 2; ++ks) {
      u16x8 pf0 = *(const u16x8*)&sP[w][lr][ks * 32 + lk * 8];
      u16x8 pf1 = *(const u16x8*)&sP[w][16 + lr][ks * 32 + lk * 8];
#pragma unroll
      for (int ni = 0; ni < 8; ++ni) {
        int vrow = ni * 16 + lr;
        u16x8 vf = *(const u16x8*)&sV[vrow][((ks * 4 + lk) ^ (vrow & 7)) * 8];
        o[0][ni] = mfma_bf16(pf0, vf, o[0][ni]);
        o[1][ni] = mfma_bf16(pf1, vf, o[1][ni]);
      }
    }
    __builtin_amdgcn_s_setprio(0);
    __syncthreads();
  }

#pragma unroll
  for (int fi = 0; fi < 2; ++fi)
#pragma unroll
    for (int r = 0; r < 4; ++r) {
      float inv = 1.0f / lrun[fi][r];
#pragma unroll
      for (int ni = 0; ni < 8; ++ni) o[fi][ni][r] *= inv;
    }
#pragma unroll
  for (int fi = 0; fi < 2; ++fi)
#pragma unroll
    for (int ni = 0; ni < 8; ++ni) {
      int dd = ni * 16 + lr;
#pragma unroll
      for (int r = 0; r < 4; ++r) {
        int sg = q0 + w * 32 + fi * 16 + lk * 4 + r;
        size_t tok = (size_t)sg * 8 + bb;
        if (dd < 64)
          aor[tok * 1024 + hh * 64 + dd] = f2bf(o[fi][ni][r]);
        else
          aoi[tok * 1024 + hh * 64 + (dd - 64)] = f2bf(o[fi][ni][r]);
      }
    }
}

// ---------------------------------------------------------------- out proj
// (round-8 proven: combined [128][re32|im32] XOR-swizzled tiles; XCD swizzle)
__global__ __launch_bounds__(256, 2) void out_gemm(
    const unsigned short* __restrict__ ar, const unsigned short* __restrict__ ai,
    const unsigned short* __restrict__ wr, const unsigned short* __restrict__ wi,
    const float* __restrict__ br, const float* __restrict__ bi,
    float* __restrict__ out) {
  __shared__ __align__(16) unsigned short smem[16384];  // 32 KB
  unsigned short (*sA)[64] = (unsigned short (*)[64])(smem);
  unsigned short (*sW)[64] = (unsigned short (*)[64])(smem + 8192);

  const int tid = threadIdx.x;
  const int lane = tid & 63;
  const int w = tid >> 6;
  const int lr = lane & 15, lk = lane >> 4;
  const int wm = (w & 1) * 64, wn = (w >> 1) * 64;

  const int lin = blockIdx.x;
  const int wg = (lin & 7) * 64 + (lin >> 3);
  const int n0 = (wg & 7) * 128;
  const int m0 = (wg >> 3) * 128;

  int srow[4], sgsw[4];
  for (int c = 0; c < 4; ++c) {
    int gid = c * 256 + tid;
    srow[c] = gid >> 3;
    sgsw[c] = (gid & 7) ^ (srow[c] & 7);
  }

  f32x4 accre[4][4], accim[4][4];
  for (int i = 0; i < 4; ++i)
    for (int j = 0; j < 4; ++j) {
      accre[i][j] = {0.f, 0.f, 0.f, 0.f};
      accim[i][j] = {0.f, 0.f, 0.f, 0.f};
    }
  const u16x8 sign8 = {0x8000, 0x8000, 0x8000, 0x8000, 0x8000, 0x8000, 0x8000, 0x8000};

  for (int k0 = 0; k0 < 1024; k0 += 32) {
    for (int c = 0; c < 4; ++c) {
      int row = srow[c], gsw = sgsw[c];
      int kcol = k0 + (gsw & 3) * 8;
      size_t aoff = (size_t)(m0 + row) * 1024 + kcol;
      gload_lds16((gsw < 4 ? ar : ai) + aoff, smem + (c * 256 + w * 64) * 8);
      size_t woff = (size_t)(n0 + row) * 1024 + kcol;
      gload_lds16((gsw < 4 ? wr : wi) + woff, smem + 8192 + (c * 256 + w * 64) * 8);
    }
    __syncthreads();

    u16x8 fWr[4], fWi[4];
    for (int ni = 0; ni < 4; ++ni) {
      int R = wn + ni * 16 + lr, sw = R & 7;
      fWr[ni] = *(const u16x8*)&sW[R][(lk ^ sw) * 8];
      fWi[ni] = *(const u16x8*)&sW[R][((4 + lk) ^ sw) * 8];
    }
    for (int mi = 0; mi < 4; ++mi) {
      int R = wm + mi * 16 + lr, sw = R & 7;
      u16x8 a_r = *(const u16x8*)&sA[R][(lk ^ sw) * 8];
      u16x8 a_i = *(const u16x8*)&sA[R][((4 + lk) ^ sw) * 8];
      u16x8 na_i = a_i ^ sign8;
      for (int ni = 0; ni < 4; ++ni) {
        accre[mi][ni] = mfma_bf16(a_r, fWr[ni], accre[mi][ni]);
        accre[mi][ni] = mfma_bf16(na_i, fWi[ni], accre[mi][ni]);
        accim[mi][ni] = mfma_bf16(a_r, fWi[ni], accim[mi][ni]);
        accim[mi][ni] = mfma_bf16(a_i, fWr[ni], accim[mi][ni]);
      }
    }
    __syncthreads();
  }

  for (int ni = 0; ni < 4; ++ni) {
    int n = n0 + wn + ni * 16 + lr;
    float vbr = br[n], vbi = bi[n];
    for (int mi = 0; mi < 4; ++mi) {
      for (int r = 0; r < 4; ++r) {
        int m = m0 + wm + mi * 16 + lk * 4 + r;
        out[(size_t)m * 1024 + n] = accre[mi][ni][r] + vbr;
        out[8388608 + (size_t)m * 1024 + n] = accim[mi][ni][r] + vbi;
      }
    }
  }
}

// ---------------------------------------------------------------- launch
extern "C" void kernel_launch(void* const* d_in, const int* in_sizes, int n_in,
                              void* d_out, int out_size, void* d_ws, size_t ws_size,
                              hipStream_t stream) {
  const float* qre = (const float*)d_in[0];
  const float* qim = (const float*)d_in[1];
  const float* kre = (const float*)d_in[2];
  const float* kim = (const float*)d_in[3];
  const float* vre = (const float*)d_in[4];
  const float* vim = (const float*)d_in[5];
  const float* wqkv_re = (const float*)d_in[6];
  const float* wqkv_im = (const float*)d_in[7];
  const float* bqr = (const float*)d_in[8];
  const float* bqi = (const float*)d_in[9];
  const float* wo_re = (const float*)d_in[10];
  const float* wo_im = (const float*)d_in[11];
  const float* bor = (const float*)d_in[12];
  const float* boi = (const float*)d_in[13];

  char* ws = (char*)d_ws;
  unsigned short* wr_bf  = (unsigned short*)(ws + 0);          //  6.29 MB
  unsigned short* wi_bf  = (unsigned short*)(ws + 6291456);
  unsigned short* wor_bf = (unsigned short*)(ws + 12582912);
  unsigned short* woi_bf = (unsigned short*)(ws + 14680064);
  // activation bf16, K-tiled batch-major (dead after proj_gemm)
  unsigned short* qreb   = (unsigned short*)(ws + 16777216);
  unsigned short* qimb   = (unsigned short*)(ws + 33554432);
  unsigned short* kreb   = (unsigned short*)(ws + 50331648);
  unsigned short* kimb   = (unsigned short*)(ws + 67108864);
  unsigned short* vreb   = (unsigned short*)(ws + 83886080);
  unsigned short* vimb   = (unsigned short*)(ws + 100663296);
  unsigned short* q2     = (unsigned short*)(ws + 117440512);  // 33.55 MB
  unsigned short* k2     = (unsigned short*)(ws + 150994944);
  unsigned short* vt     = (unsigned short*)(ws + 184549376);  // end 218.1 MB
  // attn outputs alias the dead activation region
  unsigned short* aor    = (unsigned short*)(ws + 16777216);
  unsigned short* aoi    = (unsigned short*)(ws + 33554432);

  cvt_all<<<20480, 256, 0, stream>>>(qre, qim, kre, kim, vre, vim,
                                     wqkv_re, wqkv_im, wo_re, wo_im,
                                     qreb, qimb, kreb, kimb, vreb, vimb,
                                     wr_bf, wi_bf, wor_bf, woi_bf);

  proj_gemm<<<dim3(24, 64), 256, 0, stream>>>(qreb, qimb, kreb, kimb, vreb, vimb,
                                              wr_bf, wi_bf, bqr, bqi, q2, k2, vt);
  attn_kernel<<<1024, 256, 0, stream>>>(q2, k2, vt, aor, aoi);
  out_gemm<<<512, 256, 0, stream>>>(aor, aoi, wor_bf, woi_bf, bor, boi,
                                    (float*)d_out);
}